// Round 3
// baseline (5792.492 us; speedup 1.0000x reference)
//
#include <hip/hip_runtime.h>
#include <hip/hip_bf16.h>

typedef _Float16 f16;
typedef unsigned short u16;
typedef unsigned int   u32;

__device__ __forceinline__ float h2fu(u16 u) { union { u16 s; f16 h; } t; t.s = u; return (float)t.h; }
__device__ __forceinline__ u16   f2h(float f) { union { u16 s; f16 h; } t; t.h = (f16)f; return t.s; }
__device__ __forceinline__ float geluf(float u) { return 0.5f*u*(1.0f + erff(u*0.70710678118654752f)); }
__device__ __forceinline__ float sigmf(float x) { return 1.0f/(1.0f + __expf(-x)); }
__device__ __forceinline__ float tanhfast(float x) { return 1.0f - 2.0f/(__expf(2.0f*x) + 1.0f); }

// ---------------------------------------------------------------------------
// Fused conv1(1->32,k7,p3)+bn+gelu -> conv2(32->64,k5,s2,p2)+bn+gelu.
// One block per input row r=(b*16+n).  Writes feat[(b*128+t2)*16+n][64] f16.
// ---------------------------------------------------------------------------
__global__ __launch_bounds__(256) void k_conv(
    const float* __restrict__ x,
    const float* __restrict__ w1, const float* __restrict__ cb1v,
    const float* __restrict__ g1v, const float* __restrict__ be1v,
    const float* __restrict__ w2, const float* __restrict__ cb2v,
    const float* __restrict__ g2v, const float* __restrict__ be2v,
    f16* __restrict__ feat) {
  __shared__ float xs[262];
  __shared__ float yl[32*260];     // conv1 out, padded +-2, data at +2
  __shared__ float wt[160*64];     // wt[(ic*5+kk)*64 + oc]
  __shared__ float w1l[224];
  __shared__ float cb1[32], sc1[32], sb1[32];
  __shared__ float cb2[64], sc2[64], sb2[64];
  int r = blockIdx.x, tid = threadIdx.x;
  int bb = r >> 4, n = r & 15;
  for (int i = tid; i < 262; i += 256) {
    int p = i - 3;
    xs[i] = (p >= 0 && p < 256) ? x[(size_t)r*256 + p] : 0.0f;
  }
  if (tid < 224) {
    w1l[tid] = w1[tid];
  } else {
    int oc = tid - 224;
    cb1[oc] = cb1v[oc];
    sc1[oc] = g1v[oc] * rsqrtf(1.0f + 1e-5f);
    sb1[oc] = be1v[oc];
  }
  for (int i = tid; i < 10240; i += 256) {
    int oc = i / 160, rest = i % 160;
    wt[rest*64 + oc] = w2[i];
  }
  if (tid < 64) {
    cb2[tid] = cb2v[tid];
    sc2[tid] = g2v[tid] * rsqrtf(1.0f + 1e-5f);
    sb2[tid] = be2v[tid];
  }
  for (int i = tid; i < 128; i += 256) {       // zero pads of yl
    int ic = i >> 2, z = i & 3;
    yl[ic*260 + (z < 2 ? z : 256 + z)] = 0.0f;
  }
  __syncthreads();
  float xv[7];
  #pragma unroll
  for (int k = 0; k < 7; k++) xv[k] = xs[tid + k];
  for (int oc = 0; oc < 32; oc++) {
    float acc = cb1[oc];
    #pragma unroll
    for (int k = 0; k < 7; k++) acc += w1l[oc*7 + k]*xv[k];
    float u = acc*sc1[oc] + sb1[oc];
    yl[oc*260 + 2 + tid] = geluf(u);
  }
  __syncthreads();
  int oc = tid & 63, t4 = tid >> 6;
  float acc[32];
  #pragma unroll
  for (int q = 0; q < 32; q++) acc[q] = cb2[oc];
  for (int ic = 0; ic < 32; ic++) {
    float w0 = wt[(ic*5+0)*64+oc], ww1 = wt[(ic*5+1)*64+oc], ww2 = wt[(ic*5+2)*64+oc],
          ww3 = wt[(ic*5+3)*64+oc], ww4 = wt[(ic*5+4)*64+oc];
    const float* yy = &yl[ic*260];
    #pragma unroll
    for (int q = 0; q < 32; q++) {
      int base = 8*q + 2*t4;
      float2 ya = *(const float2*)&yy[base];
      float2 yb = *(const float2*)&yy[base + 2];
      float  yc = yy[base + 4];
      acc[q] += w0*ya.x + ww1*ya.y + ww2*yb.x + ww3*yb.y + ww4*yc;
    }
  }
  #pragma unroll
  for (int q = 0; q < 32; q++) {
    int t2 = q*4 + t4;
    float u = acc[q]*sc2[oc] + sb2[oc];
    feat[(((size_t)bb*128 + t2)*16 + n)*64 + oc] = (f16)geluf(u);
  }
}

// ---------------------------------------------------------------------------
// GAT layer (+ReLU +LayerNorm).  One block per graph m (16 nodes).
// xin: (32768,16,F) f16 ; W: (F,128) f32 ; gout: (32768,16,128) f16.
// In-place safe (block reads only its own rows before writing them).
// ---------------------------------------------------------------------------
template<int F>
__global__ __launch_bounds__(256) void k_gat(
    const f16* __restrict__ xin, const float* __restrict__ W,
    const float* __restrict__ asrc, const float* __restrict__ adst,
    const float* __restrict__ gng, const float* __restrict__ gnb,
    f16* __restrict__ gout) {
  __shared__ float xl[16*F];
  __shared__ u16   WlT[128*(F+4)];       // WlT[d*(F+4)+k], f16 bits
  __shared__ float hl[16*132];
  __shared__ float vl[16*132];
  __shared__ float al[4*16*16];          // attn [h][i][j]
  __shared__ float wsrc[128], wdst[128];
  __shared__ float esl[64], edl[64];
  __shared__ float red[256], redq[256];
  __shared__ float mr[16], mrq[16];
  int m = blockIdx.x, tid = threadIdx.x;
  const f16* xr = xin + (size_t)m*(16*F);
  for (int i = tid; i < 16*F; i += 256) xl[i] = (float)xr[i];
  for (int gi = tid; gi < F*128; gi += 256) {
    int k = gi >> 7, d = gi & 127;
    WlT[d*(F+4) + k] = f2h(W[gi]);
  }
  if (tid < 128) { wsrc[tid] = asrc[tid]; wdst[tid] = adst[tid]; }
  __syncthreads();
  #pragma unroll
  for (int it = 0; it < 8; it++) {       // h = x @ W
    int o = it*256 + tid;
    int nn = o >> 7, d = o & 127;
    const u16*   wp = &WlT[d*(F+4)];
    const float* xp = &xl[nn*F];
    float acc = 0.0f;
    #pragma unroll
    for (int k = 0; k < F; k += 4) {
      uint2  wv = *(const uint2*)&wp[k];
      float4 xv = *(const float4*)&xp[k];
      acc += h2fu((u16)wv.x)*xv.x + h2fu((u16)(wv.x >> 16))*xv.y
           + h2fu((u16)wv.y)*xv.z + h2fu((u16)(wv.y >> 16))*xv.w;
    }
    hl[nn*132 + d] = acc;
  }
  __syncthreads();
  if (tid < 64) {                        // es/ed per (node, head)
    int nn = tid >> 2, hh = tid & 3;
    const float* hp  = &hl[nn*132 + hh*32];
    const float* wsp = &wsrc[hh*32];
    const float* wdp = &wdst[hh*32];
    float es = 0.0f, ed = 0.0f;
    #pragma unroll
    for (int d2 = 0; d2 < 32; d2++) { float hv = hp[d2]; es += hv*wsp[d2]; ed += hv*wdp[d2]; }
    esl[nn*4 + hh] = es; edl[nn*4 + hh] = ed;
  }
  __syncthreads();
  if (tid < 64) {                        // softmax over j per (i, head)
    int i = tid >> 2, hh = tid & 3;
    float ei = esl[i*4 + hh];
    float pv[16]; float mx = -1e30f;
    #pragma unroll
    for (int j = 0; j < 16; j++) {
      float e = ei + edl[j*4 + hh];
      e = (e < 0.0f) ? 0.2f*e : e;
      pv[j] = e; mx = fmaxf(mx, e);
    }
    float sum = 0.0f;
    #pragma unroll
    for (int j = 0; j < 16; j++) { float p = __expf(pv[j] - mx); pv[j] = p; sum += p; }
    float inv = 1.0f/sum;
    float* ap = &al[(hh*16 + i)*16];
    #pragma unroll
    for (int j = 0; j < 16; j++) ap[j] = pv[j]*inv;
  }
  __syncthreads();
  #pragma unroll
  for (int it = 0; it < 8; it++) {       // out = attn @ h, + ReLU
    int o = it*256 + tid;
    int i = o >> 7, hd = o & 127, hh = hd >> 5;
    const float* ap = &al[(hh*16 + i)*16];
    float acc = 0.0f;
    #pragma unroll
    for (int j = 0; j < 16; j++) acc += ap[j]*hl[j*132 + hd];
    vl[i*132 + hd] = fmaxf(acc, 0.0f);
  }
  __syncthreads();
  {                                      // LN stats over 128 per node
    int i = tid >> 4, s = tid & 15;
    const float* vp = &vl[i*132 + s*8];
    float sm = 0.0f, sq = 0.0f;
    #pragma unroll
    for (int d2 = 0; d2 < 8; d2++) { float v = vp[d2]; sm += v; sq += v*v; }
    red[tid] = sm; redq[tid] = sq;
  }
  __syncthreads();
  if (tid < 16) {
    float S = 0.0f, Q = 0.0f;
    #pragma unroll
    for (int s = 0; s < 16; s++) { S += red[tid*16 + s]; Q += redq[tid*16 + s]; }
    float mean = S*(1.0f/128.0f);
    float var  = Q*(1.0f/128.0f) - mean*mean;
    mr[tid] = mean; mrq[tid] = rsqrtf(var + 1e-5f);
  }
  __syncthreads();
  #pragma unroll
  for (int it = 0; it < 8; it++) {
    int o = it*256 + tid;
    int i = o >> 7, hd = o & 127;
    float v = (vl[i*132 + hd] - mr[i])*mrq[i]*gng[hd] + gnb[hd];
    gout[(size_t)m*2048 + i*128 + hd] = (f16)v;
  }
}

// ---------------------------------------------------------------------------
// C[M,N](f16) = A[M,K](f16) @ W[N,K](f32)^T + bias1(+bias2).
// 64x64 tile, BK=16, 256 threads, 4x4 microtile.  M%64==N%64==K%16==0.
// ---------------------------------------------------------------------------
__global__ __launch_bounds__(256) void k_gemm(
    const f16* __restrict__ A, const float* __restrict__ W,
    const float* __restrict__ bias1, const float* __restrict__ bias2,
    f16* __restrict__ C, int M, int N, int K) {
  __shared__ float As[16][68];
  __shared__ float Ws[16][68];
  int m0 = blockIdx.x << 6, n0 = blockIdx.y << 6;
  int tid = threadIdx.x, tx = tid & 15, ty = tid >> 4;
  int lr = tid >> 2, lk = (tid & 3) << 2;
  const u16*   Ap = (const u16*)A + (size_t)(m0 + lr)*K + lk;
  const float* Wp = W + (size_t)(n0 + lr)*K + lk;
  float acc[4][4] = {};
  for (int k0 = 0; k0 < K; k0 += 16) {
    uint2  av = *(const uint2*)(Ap + k0);
    float4 wv = *(const float4*)(Wp + k0);
    __syncthreads();
    As[lk+0][lr] = h2fu((u16)av.x); As[lk+1][lr] = h2fu((u16)(av.x >> 16));
    As[lk+2][lr] = h2fu((u16)av.y); As[lk+3][lr] = h2fu((u16)(av.y >> 16));
    Ws[lk+0][lr] = wv.x; Ws[lk+1][lr] = wv.y; Ws[lk+2][lr] = wv.z; Ws[lk+3][lr] = wv.w;
    __syncthreads();
    #pragma unroll
    for (int kk = 0; kk < 16; kk++) {
      float4 a4 = *(const float4*)&As[kk][ty << 2];
      float4 b4 = *(const float4*)&Ws[kk][tx << 2];
      acc[0][0] += a4.x*b4.x; acc[0][1] += a4.x*b4.y; acc[0][2] += a4.x*b4.z; acc[0][3] += a4.x*b4.w;
      acc[1][0] += a4.y*b4.x; acc[1][1] += a4.y*b4.y; acc[1][2] += a4.y*b4.z; acc[1][3] += a4.y*b4.w;
      acc[2][0] += a4.z*b4.x; acc[2][1] += a4.z*b4.y; acc[2][2] += a4.z*b4.z; acc[2][3] += a4.z*b4.w;
      acc[3][0] += a4.w*b4.x; acc[3][1] += a4.w*b4.y; acc[3][2] += a4.w*b4.z; acc[3][3] += a4.w*b4.w;
    }
  }
  int mrow = m0 + (ty << 2), ncol = n0 + (tx << 2);
  float bs[4];
  #pragma unroll
  for (int j = 0; j < 4; j++) {
    float bv = bias1[ncol + j];
    if (bias2) bv += bias2[ncol + j];
    bs[j] = bv;
  }
  #pragma unroll
  for (int i2 = 0; i2 < 4; i2++) {
    union { ushort4 s; f16 f[4]; } o;
    o.f[0] = (f16)(acc[i2][0] + bs[0]);
    o.f[1] = (f16)(acc[i2][1] + bs[1]);
    o.f[2] = (f16)(acc[i2][2] + bs[2]);
    o.f[3] = (f16)(acc[i2][3] + bs[3]);
    *(ushort4*)&C[(size_t)(mrow + i2)*N + ncol] = o.s;
  }
}

// ---------------------------------------------------------------------------
// LSTM recurrence, both dirs.  One block per (batch,dir), 512 threads (one
// per gate column).  whh row (f32) packed to f16 pairs in 64 u32 registers.
// pre: (B,128,512) f16 per dir.  hout: (B,128,256) f16, dir picks half.
// ---------------------------------------------------------------------------
__global__ __launch_bounds__(512) void k_lstm(
    const f16* __restrict__ pre_f, const f16* __restrict__ pre_b,
    const float* __restrict__ whh_f, const float* __restrict__ whh_b,
    f16* __restrict__ hout) {
  __shared__ float hl[128];
  __shared__ float gl[512];
  int dir = blockIdx.x & 1, b = blockIdx.x >> 1, tid = threadIdx.x;
  const f16* pre = dir ? pre_b : pre_f;
  const float* wrow = (dir ? whh_b : whh_f) + (size_t)tid*128;
  u32 wreg[64];
  #pragma unroll
  for (int q = 0; q < 64; q++) {
    float2 wv = *(const float2*)&wrow[q << 1];
    wreg[q] = (u32)f2h(wv.x) | ((u32)f2h(wv.y) << 16);
  }
  if (tid < 128) hl[tid] = 0.0f;
  float c = 0.0f;
  __syncthreads();
  for (int s = 0; s < 128; s++) {
    int t = dir ? (127 - s) : s;
    float acc = (float)pre[((size_t)b*128 + t)*512 + tid];
    #pragma unroll
    for (int q = 0; q < 64; q++) {
      u32 wv = wreg[q];
      float2 hv = *(const float2*)&hl[q << 1];
      acc += h2fu((u16)wv)*hv.x + h2fu((u16)(wv >> 16))*hv.y;
    }
    gl[tid] = acc;
    __syncthreads();
    if (tid < 128) {
      float iv = gl[tid], fv = gl[128 + tid], gv = gl[256 + tid], ov = gl[384 + tid];
      c = sigmf(fv)*c + sigmf(iv)*tanhfast(gv);
      float hv = sigmf(ov)*tanhfast(c);
      hl[tid] = hv;
      hout[((size_t)b*128 + t)*256 + (dir << 7) + tid] = (f16)hv;
    }
    __syncthreads();
  }
}

// ---------------------------------------------------------------------------
// MHA core: one block per (batch, head).  T=128, hd=64, scale=1/8.
// qkv: (32768,768) f16 ; o: (32768,256) f16 head-concat.
// ---------------------------------------------------------------------------
__global__ __launch_bounds__(256) void k_mha(const f16* __restrict__ qkv, f16* __restrict__ o) {
  __shared__ float ql[128*66];
  __shared__ float kl[128*66];
  __shared__ u16   sl[128*132];    // exp(score-max) in f16 bits
  __shared__ float invl[128];
  int b = blockIdx.x, h = blockIdx.y, tid = threadIdx.x;
  const f16* base = qkv + (size_t)b*98304 + h*64;
  for (int i = tid; i < 8192; i += 256) {
    int t = i >> 6, d = i & 63;
    ql[t*66 + d] = (float)base[t*768 + d];
    kl[t*66 + d] = (float)base[t*768 + 256 + d];
  }
  __syncthreads();
  int i = tid >> 1, jh = (tid & 1) << 6;
  const float* qp = &ql[i*66];
  float mx = -1e30f;
  for (int j = 0; j < 64; j++) {
    const float* kp = &kl[(jh + j)*66];
    float acc = 0.0f;
    #pragma unroll 8
    for (int d = 0; d < 64; d += 2) {
      float2 qv = *(const float2*)&qp[d];
      float2 kv = *(const float2*)&kp[d];
      acc += qv.x*kv.x + qv.y*kv.y;
    }
    acc *= 0.125f;
    sl[i*132 + jh + j] = f2h(acc);
    mx = fmaxf(mx, acc);
  }
  mx = fmaxf(mx, __shfl_xor(mx, 1));
  float sum = 0.0f;
  u16* sp = &sl[i*132 + jh];
  for (int j = 0; j < 64; j++) {
    float e = __expf(h2fu(sp[j]) - mx);
    sp[j] = f2h(e);
    sum += e;
  }
  sum += __shfl_xor(sum, 1);
  if ((tid & 1) == 0) invl[i] = 1.0f/sum;
  __syncthreads();
  for (int i2 = tid; i2 < 8192; i2 += 256) {     // V overwrites ql
    int t = i2 >> 6, d = i2 & 63;
    ql[t*66 + d] = (float)base[t*768 + 512 + d];
  }
  __syncthreads();
  for (int it = 0; it < 32; it++) {
    int idx = it*256 + tid;
    int oi = idx >> 6, d = idx & 63;
    const u16* pp = &sl[oi*132];
    float acc = 0.0f;
    #pragma unroll 16
    for (int j = 0; j < 128; j++) acc += h2fu(pp[j])*ql[j*66 + d];
    o[((size_t)b*128 + oi)*256 + h*64 + d] = (f16)(acc*invl[oi]);
  }
}

// ---------------------------------------------------------------------------
// att = LayerNorm(mha_out + lstm_out), width 256.  One wave per row.
// ---------------------------------------------------------------------------
__global__ __launch_bounds__(256) void k_lnres(
    const f16* __restrict__ a, const f16* __restrict__ r,
    const float* __restrict__ g, const float* __restrict__ bb, f16* __restrict__ out) {
  int row = blockIdx.x*4 + (threadIdx.x >> 6);
  int lane = threadIdx.x & 63;
  const f16* ar = a + (size_t)row*256 + lane*4;
  const f16* rr = r + (size_t)row*256 + lane*4;
  float v0 = (float)ar[0] + (float)rr[0];
  float v1 = (float)ar[1] + (float)rr[1];
  float v2 = (float)ar[2] + (float)rr[2];
  float v3 = (float)ar[3] + (float)rr[3];
  float s = v0 + v1 + v2 + v3;
  float q = v0*v0 + v1*v1 + v2*v2 + v3*v3;
  #pragma unroll
  for (int off = 32; off; off >>= 1) { s += __shfl_xor(s, off); q += __shfl_xor(q, off); }
  float mean = s*(1.0f/256.0f);
  float var  = q*(1.0f/256.0f) - mean*mean;
  float rstd = rsqrtf(var + 1e-5f);
  int d0 = lane*4;
  f16* op = out + (size_t)row*256 + d0;
  op[0] = (f16)((v0 - mean)*rstd*g[d0+0] + bb[d0+0]);
  op[1] = (f16)((v1 - mean)*rstd*g[d0+1] + bb[d0+1]);
  op[2] = (f16)((v2 - mean)*rstd*g[d0+2] + bb[d0+2]);
  op[3] = (f16)((v3 - mean)*rstd*g[d0+3] + bb[d0+3]);
}

// ---------------------------------------------------------------------------
// mean/max pool over T, LayerNorm(512), cls1+ReLU, cls2.  One block per batch.
// ---------------------------------------------------------------------------
__global__ __launch_bounds__(512) void k_pool_cls(
    const f16* __restrict__ att, const float* __restrict__ png, const float* __restrict__ pnb,
    const float* __restrict__ w1, const float* __restrict__ b1,
    const float* __restrict__ w2, const float* __restrict__ b2, float* __restrict__ out) {
  __shared__ float pl[512];
  __shared__ float redS[8], redQ[8];
  __shared__ float mrv[2];
  __shared__ float hl[128];
  int b = blockIdx.x, tid = threadIdx.x;
  if (tid < 256) {
    const f16* ar = att + (size_t)b*32768 + tid;
    float s = 0.0f, mx = -1e30f;
    for (int t = 0; t < 128; t++) { float v = (float)ar[t*256]; s += v; mx = fmaxf(mx, v); }
    pl[tid] = s*(1.0f/128.0f);
    pl[256 + tid] = mx;
  }
  __syncthreads();
  float v = pl[tid];
  float s = v, q = v*v;
  #pragma unroll
  for (int off = 32; off; off >>= 1) { s += __shfl_xor(s, off); q += __shfl_xor(q, off); }
  if ((tid & 63) == 0) { redS[tid >> 6] = s; redQ[tid >> 6] = q; }
  __syncthreads();
  if (tid == 0) {
    float S = 0.0f, Q = 0.0f;
    #pragma unroll
    for (int w = 0; w < 8; w++) { S += redS[w]; Q += redQ[w]; }
    float mean = S*(1.0f/512.0f);
    float var  = Q*(1.0f/512.0f) - mean*mean;
    mrv[0] = mean; mrv[1] = rsqrtf(var + 1e-5f);
  }
  __syncthreads();
  pl[tid] = (v - mrv[0])*mrv[1]*png[tid] + pnb[tid];
  __syncthreads();
  if (tid < 128) {
    float acc = b1[tid];
    const float* wrp = w1 + (size_t)tid*512;
    for (int d = 0; d < 512; d++) acc += pl[d]*wrp[d];
    hl[tid] = fmaxf(acc, 0.0f)*w2[tid];
  }
  __syncthreads();
  if (tid < 64) {
    float rsum = hl[tid] + hl[tid + 64];
    #pragma unroll
    for (int off = 32; off; off >>= 1) rsum += __shfl_xor(rsum, off);
    if (tid == 0) out[b] = rsum + b2[0];
  }
}

// ---------------------------------------------------------------------------
extern "C" void kernel_launch(void* const* d_in, const int* in_sizes, int n_in,
                              void* d_out, int out_size, void* d_ws, size_t ws_size,
                              hipStream_t stream) {
  (void)in_sizes; (void)n_in; (void)out_size;
  if (ws_size < (size_t)160*1024*1024) return;   // need 144 MiB; diagnostic guard
  const float* IN[47];
  for (int i = 0; i < 47; i++) IN[i] = (const float*)d_in[i];
  char* W8 = (char*)d_ws;
  // liveness-packed layout (MiB offsets), peak 144 MiB:
  f16* feat     = (f16*)(W8 + ((size_t)0  << 20));  // [0,64)   dead after GAT1
  f16* g        = (f16*)(W8 + ((size_t)64 << 20));  // [64,192)->128MiB, dead after pre GEMMs
  f16* pre_f    = (f16*)(W8 + ((size_t)0  << 20));  // [0,32)
  f16* pre_b    = (f16*)(W8 + ((size_t)32 << 20));  // [32,64)
  f16* h1       = (f16*)(W8 + ((size_t)64 << 20));  // [64,80)
  f16* lstm_out = (f16*)(W8 + ((size_t)80 << 20));  // [80,96)  live till lnres
  f16* qkv      = (f16*)(W8 + ((size_t)96 << 20));  // [96,144)
  f16* o_flat   = (f16*)(W8 + ((size_t)0  << 20));  // [0,16)
  f16* mo       = (f16*)(W8 + ((size_t)16 << 20));  // [16,32)
  f16* att      = (f16*)(W8 + ((size_t)32 << 20));  // [32,48)

  k_conv<<<4096, 256, 0, stream>>>(IN[0], IN[1], IN[2], IN[3], IN[4],
                                   IN[5], IN[6], IN[7], IN[8], feat);
  k_gat<64><<<32768, 256, 0, stream>>>(feat, IN[9], IN[10], IN[11], IN[12], IN[13], g);
  k_gat<128><<<32768, 256, 0, stream>>>(g, IN[14], IN[15], IN[16], IN[17], IN[18], g);
  {
    dim3 gr(512, 8);
    k_gemm<<<gr, 256, 0, stream>>>(g, IN[19], IN[21], IN[22], pre_f, 32768, 512, 2048);
    k_gemm<<<gr, 256, 0, stream>>>(g, IN[23], IN[25], IN[26], pre_b, 32768, 512, 2048);
  }
  k_lstm<<<512, 512, 0, stream>>>(pre_f, pre_b, IN[20], IN[24], h1);
  {
    dim3 gr(512, 8);
    k_gemm<<<gr, 256, 0, stream>>>(h1, IN[27], IN[29], IN[30], pre_f, 32768, 512, 256);
    k_gemm<<<gr, 256, 0, stream>>>(h1, IN[31], IN[33], IN[34], pre_b, 32768, 512, 256);
  }
  k_lstm<<<512, 512, 0, stream>>>(pre_f, pre_b, IN[28], IN[32], lstm_out);
  {
    dim3 gr(512, 12);
    k_gemm<<<gr, 256, 0, stream>>>(lstm_out, IN[35], IN[36], nullptr, qkv, 32768, 768, 256);
  }
  k_mha<<<dim3(256, 4), 256, 0, stream>>>(qkv, o_flat);
  {
    dim3 gr(512, 4);
    k_gemm<<<gr, 256, 0, stream>>>(o_flat, IN[37], IN[38], nullptr, mo, 32768, 256, 256);
  }
  k_lnres<<<8192, 256, 0, stream>>>(mo, lstm_out, IN[39], IN[40], att);
  k_pool_cls<<<256, 512, 0, stream>>>(att, IN[41], IN[42], IN[43], IN[44], IN[45], IN[46],
                                      (float*)d_out);
}

// Round 4
// 5000.537 us; speedup vs baseline: 1.1584x; 1.1584x over previous
//
#include <hip/hip_runtime.h>
#include <hip/hip_bf16.h>

typedef _Float16 f16;
typedef unsigned short u16;
typedef unsigned int   u32;
typedef __attribute__((ext_vector_type(8))) _Float16 f16x8;
typedef __attribute__((ext_vector_type(4))) float    f32x4;

__device__ __forceinline__ float h2fu(u16 u) { union { u16 s; f16 h; } t; t.s = u; return (float)t.h; }
__device__ __forceinline__ u16   f2h(float f) { union { u16 s; f16 h; } t; t.h = (f16)f; return t.s; }
__device__ __forceinline__ float geluf(float u) { return 0.5f*u*(1.0f + erff(u*0.70710678118654752f)); }
__device__ __forceinline__ float sigmf(float x) { return 1.0f/(1.0f + __expf(-x)); }
__device__ __forceinline__ float tanhfast(float x) { return 1.0f - 2.0f/(__expf(2.0f*x) + 1.0f); }

// ---------------------------------------------------------------------------
// Fused conv1(1->32,k7,p3)+bn+gelu -> conv2(32->64,k5,s2,p2)+bn+gelu.
// One block per input row r=(b*16+n).  Writes feat[(b*128+t2)*16+n][64] f16.
// ---------------------------------------------------------------------------
__global__ __launch_bounds__(256) void k_conv(
    const float* __restrict__ x,
    const float* __restrict__ w1, const float* __restrict__ cb1v,
    const float* __restrict__ g1v, const float* __restrict__ be1v,
    const float* __restrict__ w2, const float* __restrict__ cb2v,
    const float* __restrict__ g2v, const float* __restrict__ be2v,
    f16* __restrict__ feat) {
  __shared__ float xs[262];
  __shared__ float yl[32*260];     // conv1 out, padded +-2, data at +2
  __shared__ float wt[160*64];     // wt[(ic*5+kk)*64 + oc]
  __shared__ float w1l[224];
  __shared__ float cb1[32], sc1[32], sb1[32];
  __shared__ float cb2[64], sc2[64], sb2[64];
  int r = blockIdx.x, tid = threadIdx.x;
  int bb = r >> 4, n = r & 15;
  for (int i = tid; i < 262; i += 256) {
    int p = i - 3;
    xs[i] = (p >= 0 && p < 256) ? x[(size_t)r*256 + p] : 0.0f;
  }
  if (tid < 224) {
    w1l[tid] = w1[tid];
  } else {
    int oc = tid - 224;
    cb1[oc] = cb1v[oc];
    sc1[oc] = g1v[oc] * rsqrtf(1.0f + 1e-5f);
    sb1[oc] = be1v[oc];
  }
  for (int i = tid; i < 10240; i += 256) {
    int oc = i / 160, rest = i % 160;
    wt[rest*64 + oc] = w2[i];
  }
  if (tid < 64) {
    cb2[tid] = cb2v[tid];
    sc2[tid] = g2v[tid] * rsqrtf(1.0f + 1e-5f);
    sb2[tid] = be2v[tid];
  }
  for (int i = tid; i < 128; i += 256) {       // zero pads of yl
    int ic = i >> 2, z = i & 3;
    yl[ic*260 + (z < 2 ? z : 256 + z)] = 0.0f;
  }
  __syncthreads();
  float xv[7];
  #pragma unroll
  for (int k = 0; k < 7; k++) xv[k] = xs[tid + k];
  for (int oc = 0; oc < 32; oc++) {
    float acc = cb1[oc];
    #pragma unroll
    for (int k = 0; k < 7; k++) acc += w1l[oc*7 + k]*xv[k];
    float u = acc*sc1[oc] + sb1[oc];
    yl[oc*260 + 2 + tid] = geluf(u);
  }
  __syncthreads();
  int oc = tid & 63, t4 = tid >> 6;
  float acc[32];
  #pragma unroll
  for (int q = 0; q < 32; q++) acc[q] = cb2[oc];
  for (int ic = 0; ic < 32; ic++) {
    float w0 = wt[(ic*5+0)*64+oc], ww1 = wt[(ic*5+1)*64+oc], ww2 = wt[(ic*5+2)*64+oc],
          ww3 = wt[(ic*5+3)*64+oc], ww4 = wt[(ic*5+4)*64+oc];
    const float* yy = &yl[ic*260];
    #pragma unroll
    for (int q = 0; q < 32; q++) {
      int base = 8*q + 2*t4;
      float2 ya = *(const float2*)&yy[base];
      float2 yb = *(const float2*)&yy[base + 2];
      float  yc = yy[base + 4];
      acc[q] += w0*ya.x + ww1*ya.y + ww2*yb.x + ww3*yb.y + ww4*yc;
    }
  }
  #pragma unroll
  for (int q = 0; q < 32; q++) {
    int t2 = q*4 + t4;
    float u = acc[q]*sc2[oc] + sb2[oc];
    feat[(((size_t)bb*128 + t2)*16 + n)*64 + oc] = (f16)geluf(u);
  }
}

// ---------------------------------------------------------------------------
// GAT layer (+ReLU +LayerNorm) via MFMA.  One block = 8 graphs (128 rows),
// 256 threads (4 waves).  h = x@W as 128x128xF MFMA GEMM in LDS, then fused
// attention + LN.  In-place safe (block reads its rows before writing them).
// xin: (32768*16, F) f16 ; W: (F,128) f32 ; gout: (32768*16, 128) f16.
// ---------------------------------------------------------------------------
template<int F>
__global__ __launch_bounds__(256) void k_gat_mfma(
    const f16* __restrict__ xin, const float* __restrict__ W,
    const float* __restrict__ asrc, const float* __restrict__ adst,
    const float* __restrict__ gng, const float* __restrict__ gnb,
    f16* __restrict__ gout) {
  constexpr int XP = F + 8;            // x row stride (u16), 16B-aligned rows
  __shared__ __align__(16) u16 xa[128*XP];   // x ; later attn (needs 8192 u16 <= 128*72)
  __shared__ __align__(16) u16 wt[128*XP];   // W^T [c][k] f16
  __shared__ float hb[128*129];              // h f32, odd stride -> bank-spread
  __shared__ float esl[512], edl[512];       // [g][n*4+hh]
  __shared__ float wsv[128], wdv[128];
  int tid = threadIdx.x;
  size_t rowbase = (size_t)blockIdx.x*128;
  // stage x (contiguous 128*F f16)
  const u32* xg = (const u32*)(xin + rowbase*F);
  for (int i = tid; i < 128*F/2; i += 256) {
    u32 v = xg[i];
    int r = (2*i)/F, k = (2*i)%F;
    *(u32*)&xa[r*XP + k] = v;
  }
  // stage W transposed + f32->f16
  for (int i = tid; i < F*128; i += 256) {
    int k = i >> 7, c = i & 127;
    wt[c*XP + k] = f2h(W[i]);
  }
  if (tid < 128) { wsv[tid] = asrc[tid]; wdv[tid] = adst[tid]; }
  __syncthreads();
  // ---- MFMA: h[128][128] = x[128][F] @ W[F][128] ----
  int wave = tid >> 6, lane = tid & 63;
  int lr = lane & 15, lg = lane >> 4;
  #pragma unroll
  for (int mi = 0; mi < 2; mi++) {
    int mt = wave*2 + mi;
    f16x8 af[F/32];
    #pragma unroll
    for (int kb = 0; kb < F/32; kb++)
      af[kb] = *(const f16x8*)&xa[(mt*16 + lr)*XP + kb*32 + lg*8];
    #pragma unroll
    for (int nt = 0; nt < 8; nt++) {
      f32x4 acc = {0.0f, 0.0f, 0.0f, 0.0f};
      #pragma unroll
      for (int kb = 0; kb < F/32; kb++) {
        f16x8 bf = *(const f16x8*)&wt[(nt*16 + lr)*XP + kb*32 + lg*8];
        acc = __builtin_amdgcn_mfma_f32_16x16x32_f16(af[kb], bf, acc, 0, 0, 0);
      }
      #pragma unroll
      for (int q = 0; q < 4; q++)
        hb[(mt*16 + lg*4 + q)*129 + nt*16 + lr] = acc[q];
    }
  }
  __syncthreads();
  // ---- es/ed per (graph, node, head) ----
  int g = tid >> 5, l32 = tid & 31;
  #pragma unroll
  for (int q = 0; q < 2; q++) {
    int p = l32 + 32*q;               // p = n*4 + hh
    int n = p >> 2, hh = p & 3;
    const float* hp  = &hb[(g*16 + n)*129 + hh*32];
    const float* wsp = &wsv[hh*32];
    const float* wdp = &wdv[hh*32];
    float es = 0.0f, ed = 0.0f;
    #pragma unroll
    for (int d = 0; d < 32; d++) { float hv = hp[d]; es += hv*wsp[d]; ed += hv*wdp[d]; }
    esl[g*64 + p] = es; edl[g*64 + p] = ed;
  }
  __syncthreads();
  // ---- softmax over j per (graph, i, head); attn as f16 in xa ----
  u16* al = xa;                        // al[((g*4+hh)*16 + i)*16 + j]
  #pragma unroll
  for (int q = 0; q < 2; q++) {
    int p = l32 + 32*q;
    int i = p >> 2, hh = p & 3;
    float ei = esl[g*64 + p];
    float pv[16]; float mx = -1e30f;
    #pragma unroll
    for (int j = 0; j < 16; j++) {
      float e = ei + edl[g*64 + j*4 + hh];
      e = (e < 0.0f) ? 0.2f*e : e;
      pv[j] = e; mx = fmaxf(mx, e);
    }
    float sum = 0.0f;
    #pragma unroll
    for (int j = 0; j < 16; j++) { float pe = __expf(pv[j] - mx); pv[j] = pe; sum += pe; }
    float inv = 1.0f/sum;
    u16* ap = &al[((g*4 + hh)*16 + i)*16];
    #pragma unroll
    for (int j = 0; j < 16; j++) ap[j] = f2h(pv[j]*inv);
  }
  __syncthreads();
  // ---- out = attn@h, ReLU, LayerNorm(128), write ----
  int rloc = tid >> 1;                 // 0..127
  int gg = rloc >> 4, ii = rloc & 15;
  int half = tid & 1;                  // dims [64*half, 64*half+64)
  float o[64];
  #pragma unroll
  for (int hhh = 0; hhh < 2; hhh++) {
    int hh = half*2 + hhh;
    const u16* ap = &al[((gg*4 + hh)*16 + ii)*16];
    f16x8 a0 = *(const f16x8*)&ap[0];
    f16x8 a1 = *(const f16x8*)&ap[8];
    float aw[16];
    #pragma unroll
    for (int j = 0; j < 8; j++) { aw[j] = (float)a0[j]; aw[8 + j] = (float)a1[j]; }
    #pragma unroll
    for (int dd = 0; dd < 32; dd++) {
      int d = hh*32 + dd;
      float acc = 0.0f;
      #pragma unroll
      for (int j = 0; j < 16; j++) acc += aw[j]*hb[(gg*16 + j)*129 + d];
      o[hhh*32 + dd] = fmaxf(acc, 0.0f);
    }
  }
  float s = 0.0f, sq = 0.0f;
  #pragma unroll
  for (int k = 0; k < 64; k++) { s += o[k]; sq += o[k]*o[k]; }
  s  += __shfl_xor(s, 1);
  sq += __shfl_xor(sq, 1);
  float mean = s*(1.0f/128.0f);
  float var  = sq*(1.0f/128.0f) - mean*mean;
  float rstd = rsqrtf(var + 1e-5f);
  f16* orow = gout + (rowbase + rloc)*128 + half*64;
  #pragma unroll
  for (int k = 0; k < 64; k++) {
    int d = half*64 + k;
    orow[k] = (f16)((o[k] - mean)*rstd*gng[d] + gnb[d]);
  }
}

// ---------------------------------------------------------------------------
// C[M,N](f16) = A[M,K](f16) @ W[N,K](f32)^T + bias1(+bias2).
// 64x64 tile, BK=16, 256 threads, 4x4 microtile.  M%64==N%64==K%16==0.
// ---------------------------------------------------------------------------
__global__ __launch_bounds__(256) void k_gemm(
    const f16* __restrict__ A, const float* __restrict__ W,
    const float* __restrict__ bias1, const float* __restrict__ bias2,
    f16* __restrict__ C, int M, int N, int K) {
  __shared__ float As[16][68];
  __shared__ float Ws[16][68];
  int m0 = blockIdx.x << 6, n0 = blockIdx.y << 6;
  int tid = threadIdx.x, tx = tid & 15, ty = tid >> 4;
  int lr = tid >> 2, lk = (tid & 3) << 2;
  const u16*   Ap = (const u16*)A + (size_t)(m0 + lr)*K + lk;
  const float* Wp = W + (size_t)(n0 + lr)*K + lk;
  float acc[4][4] = {};
  for (int k0 = 0; k0 < K; k0 += 16) {
    uint2  av = *(const uint2*)(Ap + k0);
    float4 wv = *(const float4*)(Wp + k0);
    __syncthreads();
    As[lk+0][lr] = h2fu((u16)av.x); As[lk+1][lr] = h2fu((u16)(av.x >> 16));
    As[lk+2][lr] = h2fu((u16)av.y); As[lk+3][lr] = h2fu((u16)(av.y >> 16));
    Ws[lk+0][lr] = wv.x; Ws[lk+1][lr] = wv.y; Ws[lk+2][lr] = wv.z; Ws[lk+3][lr] = wv.w;
    __syncthreads();
    #pragma unroll
    for (int kk = 0; kk < 16; kk++) {
      float4 a4 = *(const float4*)&As[kk][ty << 2];
      float4 b4 = *(const float4*)&Ws[kk][tx << 2];
      acc[0][0] += a4.x*b4.x; acc[0][1] += a4.x*b4.y; acc[0][2] += a4.x*b4.z; acc[0][3] += a4.x*b4.w;
      acc[1][0] += a4.y*b4.x; acc[1][1] += a4.y*b4.y; acc[1][2] += a4.y*b4.z; acc[1][3] += a4.y*b4.w;
      acc[2][0] += a4.z*b4.x; acc[2][1] += a4.z*b4.y; acc[2][2] += a4.z*b4.z; acc[2][3] += a4.z*b4.w;
      acc[3][0] += a4.w*b4.x; acc[3][1] += a4.w*b4.y; acc[3][2] += a4.w*b4.z; acc[3][3] += a4.w*b4.w;
    }
  }
  int mrow = m0 + (ty << 2), ncol = n0 + (tx << 2);
  float bs[4];
  #pragma unroll
  for (int j = 0; j < 4; j++) {
    float bv = bias1[ncol + j];
    if (bias2) bv += bias2[ncol + j];
    bs[j] = bv;
  }
  #pragma unroll
  for (int i2 = 0; i2 < 4; i2++) {
    union { ushort4 s; f16 f[4]; } o;
    o.f[0] = (f16)(acc[i2][0] + bs[0]);
    o.f[1] = (f16)(acc[i2][1] + bs[1]);
    o.f[2] = (f16)(acc[i2][2] + bs[2]);
    o.f[3] = (f16)(acc[i2][3] + bs[3]);
    *(ushort4*)&C[(size_t)(mrow + i2)*N + ncol] = o.s;
  }
}

// ---------------------------------------------------------------------------
// LSTM recurrence, both dirs.  One block per (batch,dir), 512 threads (one
// per gate column).  whh row (f32) packed to f16 pairs in 64 u32 registers.
// pre: (B,128,512) f16 per dir.  hout: (B,128,256) f16, dir picks half.
// ---------------------------------------------------------------------------
__global__ __launch_bounds__(512) void k_lstm(
    const f16* __restrict__ pre_f, const f16* __restrict__ pre_b,
    const float* __restrict__ whh_f, const float* __restrict__ whh_b,
    f16* __restrict__ hout) {
  __shared__ float hl[128];
  __shared__ float gl[512];
  int dir = blockIdx.x & 1, b = blockIdx.x >> 1, tid = threadIdx.x;
  const f16* pre = dir ? pre_b : pre_f;
  const float* wrow = (dir ? whh_b : whh_f) + (size_t)tid*128;
  u32 wreg[64];
  #pragma unroll
  for (int q = 0; q < 64; q++) {
    float2 wv = *(const float2*)&wrow[q << 1];
    wreg[q] = (u32)f2h(wv.x) | ((u32)f2h(wv.y) << 16);
  }
  if (tid < 128) hl[tid] = 0.0f;
  float c = 0.0f;
  __syncthreads();
  for (int s = 0; s < 128; s++) {
    int t = dir ? (127 - s) : s;
    float acc = (float)pre[((size_t)b*128 + t)*512 + tid];
    #pragma unroll
    for (int q = 0; q < 64; q++) {
      u32 wv = wreg[q];
      float2 hv = *(const float2*)&hl[q << 1];
      acc += h2fu((u16)wv)*hv.x + h2fu((u16)(wv >> 16))*hv.y;
    }
    gl[tid] = acc;
    __syncthreads();
    if (tid < 128) {
      float iv = gl[tid], fv = gl[128 + tid], gv = gl[256 + tid], ov = gl[384 + tid];
      c = sigmf(fv)*c + sigmf(iv)*tanhfast(gv);
      float hv = sigmf(ov)*tanhfast(c);
      hl[tid] = hv;
      hout[((size_t)b*128 + t)*256 + (dir << 7) + tid] = (f16)hv;
    }
    __syncthreads();
  }
}

// ---------------------------------------------------------------------------
// MHA core: one block per (batch, head).  T=128, hd=64, scale=1/8.
// qkv: (32768,768) f16 ; o: (32768,256) f16 head-concat.
// ---------------------------------------------------------------------------
__global__ __launch_bounds__(256) void k_mha(const f16* __restrict__ qkv, f16* __restrict__ o) {
  __shared__ float ql[128*66];
  __shared__ float kl[128*66];
  __shared__ u16   sl[128*132];    // exp(score-max) in f16 bits
  __shared__ float invl[128];
  int b = blockIdx.x, h = blockIdx.y, tid = threadIdx.x;
  const f16* base = qkv + (size_t)b*98304 + h*64;
  for (int i = tid; i < 8192; i += 256) {
    int t = i >> 6, d = i & 63;
    ql[t*66 + d] = (float)base[t*768 + d];
    kl[t*66 + d] = (float)base[t*768 + 256 + d];
  }
  __syncthreads();
  int i = tid >> 1, jh = (tid & 1) << 6;
  const float* qp = &ql[i*66];
  float mx = -1e30f;
  for (int j = 0; j < 64; j++) {
    const float* kp = &kl[(jh + j)*66];
    float acc = 0.0f;
    #pragma unroll 8
    for (int d = 0; d < 64; d += 2) {
      float2 qv = *(const float2*)&qp[d];
      float2 kv = *(const float2*)&kp[d];
      acc += qv.x*kv.x + qv.y*kv.y;
    }
    acc *= 0.125f;
    sl[i*132 + jh + j] = f2h(acc);
    mx = fmaxf(mx, acc);
  }
  mx = fmaxf(mx, __shfl_xor(mx, 1));
  float sum = 0.0f;
  u16* sp = &sl[i*132 + jh];
  for (int j = 0; j < 64; j++) {
    float e = __expf(h2fu(sp[j]) - mx);
    sp[j] = f2h(e);
    sum += e;
  }
  sum += __shfl_xor(sum, 1);
  if ((tid & 1) == 0) invl[i] = 1.0f/sum;
  __syncthreads();
  for (int i2 = tid; i2 < 8192; i2 += 256) {     // V overwrites ql
    int t = i2 >> 6, d = i2 & 63;
    ql[t*66 + d] = (float)base[t*768 + 512 + d];
  }
  __syncthreads();
  for (int it = 0; it < 32; it++) {
    int idx = it*256 + tid;
    int oi = idx >> 6, d = idx & 63;
    const u16* pp = &sl[oi*132];
    float acc = 0.0f;
    #pragma unroll 16
    for (int j = 0; j < 128; j++) acc += h2fu(pp[j])*ql[j*66 + d];
    o[((size_t)b*128 + oi)*256 + h*64 + d] = (f16)(acc*invl[oi]);
  }
}

// ---------------------------------------------------------------------------
// att = LayerNorm(mha_out + lstm_out), width 256.  One wave per row.
// ---------------------------------------------------------------------------
__global__ __launch_bounds__(256) void k_lnres(
    const f16* __restrict__ a, const f16* __restrict__ r,
    const float* __restrict__ g, const float* __restrict__ bb, f16* __restrict__ out) {
  int row = blockIdx.x*4 + (threadIdx.x >> 6);
  int lane = threadIdx.x & 63;
  const f16* ar = a + (size_t)row*256 + lane*4;
  const f16* rr = r + (size_t)row*256 + lane*4;
  float v0 = (float)ar[0] + (float)rr[0];
  float v1 = (float)ar[1] + (float)rr[1];
  float v2 = (float)ar[2] + (float)rr[2];
  float v3 = (float)ar[3] + (float)rr[3];
  float s = v0 + v1 + v2 + v3;
  float q = v0*v0 + v1*v1 + v2*v2 + v3*v3;
  #pragma unroll
  for (int off = 32; off; off >>= 1) { s += __shfl_xor(s, off); q += __shfl_xor(q, off); }
  float mean = s*(1.0f/256.0f);
  float var  = q*(1.0f/256.0f) - mean*mean;
  float rstd = rsqrtf(var + 1e-5f);
  int d0 = lane*4;
  f16* op = out + (size_t)row*256 + d0;
  op[0] = (f16)((v0 - mean)*rstd*g[d0+0] + bb[d0+0]);
  op[1] = (f16)((v1 - mean)*rstd*g[d0+1] + bb[d0+1]);
  op[2] = (f16)((v2 - mean)*rstd*g[d0+2] + bb[d0+2]);
  op[3] = (f16)((v3 - mean)*rstd*g[d0+3] + bb[d0+3]);
}

// ---------------------------------------------------------------------------
// mean/max pool over T, LayerNorm(512), cls1+ReLU, cls2.  One block per batch.
// ---------------------------------------------------------------------------
__global__ __launch_bounds__(512) void k_pool_cls(
    const f16* __restrict__ att, const float* __restrict__ png, const float* __restrict__ pnb,
    const float* __restrict__ w1, const float* __restrict__ b1,
    const float* __restrict__ w2, const float* __restrict__ b2, float* __restrict__ out) {
  __shared__ float pl[512];
  __shared__ float redS[8], redQ[8];
  __shared__ float mrv[2];
  __shared__ float hl[128];
  int b = blockIdx.x, tid = threadIdx.x;
  if (tid < 256) {
    const f16* ar = att + (size_t)b*32768 + tid;
    float s = 0.0f, mx = -1e30f;
    for (int t = 0; t < 128; t++) { float v = (float)ar[t*256]; s += v; mx = fmaxf(mx, v); }
    pl[tid] = s*(1.0f/128.0f);
    pl[256 + tid] = mx;
  }
  __syncthreads();
  float v = pl[tid];
  float s = v, q = v*v;
  #pragma unroll
  for (int off = 32; off; off >>= 1) { s += __shfl_xor(s, off); q += __shfl_xor(q, off); }
  if ((tid & 63) == 0) { redS[tid >> 6] = s; redQ[tid >> 6] = q; }
  __syncthreads();
  if (tid == 0) {
    float S = 0.0f, Q = 0.0f;
    #pragma unroll
    for (int w = 0; w < 8; w++) { S += redS[w]; Q += redQ[w]; }
    float mean = S*(1.0f/512.0f);
    float var  = Q*(1.0f/512.0f) - mean*mean;
    mrv[0] = mean; mrv[1] = rsqrtf(var + 1e-5f);
  }
  __syncthreads();
  pl[tid] = (v - mrv[0])*mrv[1]*png[tid] + pnb[tid];
  __syncthreads();
  if (tid < 128) {
    float acc = b1[tid];
    const float* wrp = w1 + (size_t)tid*512;
    for (int d = 0; d < 512; d++) acc += pl[d]*wrp[d];
    hl[tid] = fmaxf(acc, 0.0f)*w2[tid];
  }
  __syncthreads();
  if (tid < 64) {
    float rsum = hl[tid] + hl[tid + 64];
    #pragma unroll
    for (int off = 32; off; off >>= 1) rsum += __shfl_xor(rsum, off);
    if (tid == 0) out[b] = rsum + b2[0];
  }
}

// ---------------------------------------------------------------------------
extern "C" void kernel_launch(void* const* d_in, const int* in_sizes, int n_in,
                              void* d_out, int out_size, void* d_ws, size_t ws_size,
                              hipStream_t stream) {
  (void)in_sizes; (void)n_in; (void)out_size;
  if (ws_size < (size_t)192*1024*1024) return;   // round-3 proved >=192 MiB present
  const float* IN[47];
  for (int i = 0; i < 47; i++) IN[i] = (const float*)d_in[i];
  char* W8 = (char*)d_ws;
  // liveness-packed layout (MiB offsets), peak 192 MiB:
  f16* feat     = (f16*)(W8 + ((size_t)0  << 20));  // [0,64)   dead after GAT1
  f16* g        = (f16*)(W8 + ((size_t)64 << 20));  // [64,192) dead after pre GEMMs
  f16* pre_f    = (f16*)(W8 + ((size_t)0  << 20));  // [0,32)
  f16* pre_b    = (f16*)(W8 + ((size_t)32 << 20));  // [32,64)
  f16* h1       = (f16*)(W8 + ((size_t)64 << 20));  // [64,80)
  f16* lstm_out = (f16*)(W8 + ((size_t)80 << 20));  // [80,96)  live till lnres
  f16* qkv      = (f16*)(W8 + ((size_t)96 << 20));  // [96,144)
  f16* o_flat   = (f16*)(W8 + ((size_t)0  << 20));  // [0,16)
  f16* mo       = (f16*)(W8 + ((size_t)16 << 20));  // [16,32)
  f16* att      = (f16*)(W8 + ((size_t)32 << 20));  // [32,48)

  k_conv<<<4096, 256, 0, stream>>>(IN[0], IN[1], IN[2], IN[3], IN[4],
                                   IN[5], IN[6], IN[7], IN[8], feat);
  k_gat_mfma<64><<<4096, 256, 0, stream>>>(feat, IN[9], IN[10], IN[11], IN[12], IN[13], g);
  k_gat_mfma<128><<<4096, 256, 0, stream>>>(g, IN[14], IN[15], IN[16], IN[17], IN[18], g);
  {
    dim3 gr(512, 8);
    k_gemm<<<gr, 256, 0, stream>>>(g, IN[19], IN[21], IN[22], pre_f, 32768, 512, 2048);
    k_gemm<<<gr, 256, 0, stream>>>(g, IN[23], IN[25], IN[26], pre_b, 32768, 512, 2048);
  }
  k_lstm<<<512, 512, 0, stream>>>(pre_f, pre_b, IN[20], IN[24], h1);
  {
    dim3 gr(512, 8);
    k_gemm<<<gr, 256, 0, stream>>>(h1, IN[27], IN[29], IN[30], pre_f, 32768, 512, 256);
    k_gemm<<<gr, 256, 0, stream>>>(h1, IN[31], IN[33], IN[34], pre_b, 32768, 512, 256);
  }
  k_lstm<<<512, 512, 0, stream>>>(pre_f, pre_b, IN[28], IN[32], lstm_out);
  {
    dim3 gr(512, 12);
    k_gemm<<<gr, 256, 0, stream>>>(lstm_out, IN[35], IN[36], nullptr, qkv, 32768, 768, 256);
  }
  k_mha<<<dim3(256, 4), 256, 0, stream>>>(qkv, o_flat);
  {
    dim3 gr(512, 4);
    k_gemm<<<gr, 256, 0, stream>>>(o_flat, IN[37], IN[38], nullptr, mo, 32768, 256, 256);
  }
  k_lnres<<<8192, 256, 0, stream>>>(mo, lstm_out, IN[39], IN[40], att);
  k_pool_cls<<<256, 512, 0, stream>>>(att, IN[41], IN[42], IN[43], IN[44], IN[45], IN[46],
                                      (float*)d_out);
}

// Round 5
// 2854.293 us; speedup vs baseline: 2.0294x; 1.7519x over previous
//
#include <hip/hip_runtime.h>
#include <hip/hip_bf16.h>

typedef _Float16 f16;
typedef unsigned short u16;
typedef unsigned int   u32;
typedef __attribute__((ext_vector_type(8))) _Float16 f16x8;
typedef __attribute__((ext_vector_type(4))) float    f32x4;

__device__ __forceinline__ float h2fu(u16 u) { union { u16 s; f16 h; } t; t.s = u; return (float)t.h; }
__device__ __forceinline__ u16   f2h(float f) { union { u16 s; f16 h; } t; t.h = (f16)f; return t.s; }
__device__ __forceinline__ float geluf(float u) { return 0.5f*u*(1.0f + erff(u*0.70710678118654752f)); }
__device__ __forceinline__ float sigmf(float x) { return 1.0f/(1.0f + __expf(-x)); }
__device__ __forceinline__ float tanhfast(float x) { return 1.0f - 2.0f/(__expf(2.0f*x) + 1.0f); }

// ---------------------------------------------------------------------------
// Fused conv1(1->32,k7,p3)+bn+gelu -> conv2(32->64,k5,s2,p2)+bn+gelu.
// One block per input row r=(b*16+n).  Writes feat[(b*128+t2)*16+n][64] f16.
// ---------------------------------------------------------------------------
__global__ __launch_bounds__(256) void k_conv(
    const float* __restrict__ x,
    const float* __restrict__ w1, const float* __restrict__ cb1v,
    const float* __restrict__ g1v, const float* __restrict__ be1v,
    const float* __restrict__ w2, const float* __restrict__ cb2v,
    const float* __restrict__ g2v, const float* __restrict__ be2v,
    f16* __restrict__ feat) {
  __shared__ float xs[262];
  __shared__ float yl[32*260];     // conv1 out, padded +-2, data at +2
  __shared__ float wt[160*64];     // wt[(ic*5+kk)*64 + oc]
  __shared__ float w1l[224];
  __shared__ float cb1[32], sc1[32], sb1[32];
  __shared__ float cb2[64], sc2[64], sb2[64];
  int r = blockIdx.x, tid = threadIdx.x;
  int bb = r >> 4, n = r & 15;
  for (int i = tid; i < 262; i += 256) {
    int p = i - 3;
    xs[i] = (p >= 0 && p < 256) ? x[(size_t)r*256 + p] : 0.0f;
  }
  if (tid < 224) {
    w1l[tid] = w1[tid];
  } else {
    int oc = tid - 224;
    cb1[oc] = cb1v[oc];
    sc1[oc] = g1v[oc] * rsqrtf(1.0f + 1e-5f);
    sb1[oc] = be1v[oc];
  }
  for (int i = tid; i < 10240; i += 256) {
    int oc = i / 160, rest = i % 160;
    wt[rest*64 + oc] = w2[i];
  }
  if (tid < 64) {
    cb2[tid] = cb2v[tid];
    sc2[tid] = g2v[tid] * rsqrtf(1.0f + 1e-5f);
    sb2[tid] = be2v[tid];
  }
  for (int i = tid; i < 128; i += 256) {       // zero pads of yl
    int ic = i >> 2, z = i & 3;
    yl[ic*260 + (z < 2 ? z : 256 + z)] = 0.0f;
  }
  __syncthreads();
  float xv[7];
  #pragma unroll
  for (int k = 0; k < 7; k++) xv[k] = xs[tid + k];
  for (int oc = 0; oc < 32; oc++) {
    float acc = cb1[oc];
    #pragma unroll
    for (int k = 0; k < 7; k++) acc += w1l[oc*7 + k]*xv[k];
    float u = acc*sc1[oc] + sb1[oc];
    yl[oc*260 + 2 + tid] = geluf(u);
  }
  __syncthreads();
  int oc = tid & 63, t4 = tid >> 6;
  float acc[32];
  #pragma unroll
  for (int q = 0; q < 32; q++) acc[q] = cb2[oc];
  for (int ic = 0; ic < 32; ic++) {
    float w0 = wt[(ic*5+0)*64+oc], ww1 = wt[(ic*5+1)*64+oc], ww2 = wt[(ic*5+2)*64+oc],
          ww3 = wt[(ic*5+3)*64+oc], ww4 = wt[(ic*5+4)*64+oc];
    const float* yy = &yl[ic*260];
    #pragma unroll
    for (int q = 0; q < 32; q++) {
      int base = 8*q + 2*t4;
      float2 ya = *(const float2*)&yy[base];
      float2 yb = *(const float2*)&yy[base + 2];
      float  yc = yy[base + 4];
      acc[q] += w0*ya.x + ww1*ya.y + ww2*yb.x + ww3*yb.y + ww4*yc;
    }
  }
  #pragma unroll
  for (int q = 0; q < 32; q++) {
    int t2 = q*4 + t4;
    float u = acc[q]*sc2[oc] + sb2[oc];
    feat[(((size_t)bb*128 + t2)*16 + n)*64 + oc] = (f16)geluf(u);
  }
}

// ---------------------------------------------------------------------------
// GAT layer (+ReLU +LayerNorm) via MFMA.  One block = 8 graphs (128 rows),
// 256 threads (4 waves).  (unchanged from round 4 — validated)
// ---------------------------------------------------------------------------
template<int F>
__global__ __launch_bounds__(256) void k_gat_mfma(
    const f16* __restrict__ xin, const float* __restrict__ W,
    const float* __restrict__ asrc, const float* __restrict__ adst,
    const float* __restrict__ gng, const float* __restrict__ gnb,
    f16* __restrict__ gout) {
  constexpr int XP = F + 8;
  __shared__ __align__(16) u16 xa[128*XP];
  __shared__ __align__(16) u16 wt[128*XP];
  __shared__ float hb[128*129];
  __shared__ float esl[512], edl[512];
  __shared__ float wsv[128], wdv[128];
  int tid = threadIdx.x;
  size_t rowbase = (size_t)blockIdx.x*128;
  const u32* xg = (const u32*)(xin + rowbase*F);
  for (int i = tid; i < 128*F/2; i += 256) {
    u32 v = xg[i];
    int r = (2*i)/F, k = (2*i)%F;
    *(u32*)&xa[r*XP + k] = v;
  }
  for (int i = tid; i < F*128; i += 256) {
    int k = i >> 7, c = i & 127;
    wt[c*XP + k] = f2h(W[i]);
  }
  if (tid < 128) { wsv[tid] = asrc[tid]; wdv[tid] = adst[tid]; }
  __syncthreads();
  int wave = tid >> 6, lane = tid & 63;
  int lr = lane & 15, lg = lane >> 4;
  #pragma unroll
  for (int mi = 0; mi < 2; mi++) {
    int mt = wave*2 + mi;
    f16x8 af[F/32];
    #pragma unroll
    for (int kb = 0; kb < F/32; kb++)
      af[kb] = *(const f16x8*)&xa[(mt*16 + lr)*XP + kb*32 + lg*8];
    #pragma unroll
    for (int nt = 0; nt < 8; nt++) {
      f32x4 acc = {0.0f, 0.0f, 0.0f, 0.0f};
      #pragma unroll
      for (int kb = 0; kb < F/32; kb++) {
        f16x8 bf = *(const f16x8*)&wt[(nt*16 + lr)*XP + kb*32 + lg*8];
        acc = __builtin_amdgcn_mfma_f32_16x16x32_f16(af[kb], bf, acc, 0, 0, 0);
      }
      #pragma unroll
      for (int q = 0; q < 4; q++)
        hb[(mt*16 + lg*4 + q)*129 + nt*16 + lr] = acc[q];
    }
  }
  __syncthreads();
  int g = tid >> 5, l32 = tid & 31;
  #pragma unroll
  for (int q = 0; q < 2; q++) {
    int p = l32 + 32*q;
    int n = p >> 2, hh = p & 3;
    const float* hp  = &hb[(g*16 + n)*129 + hh*32];
    const float* wsp = &wsv[hh*32];
    const float* wdp = &wdv[hh*32];
    float es = 0.0f, ed = 0.0f;
    #pragma unroll
    for (int d = 0; d < 32; d++) { float hv = hp[d]; es += hv*wsp[d]; ed += hv*wdp[d]; }
    esl[g*64 + p] = es; edl[g*64 + p] = ed;
  }
  __syncthreads();
  u16* al = xa;
  #pragma unroll
  for (int q = 0; q < 2; q++) {
    int p = l32 + 32*q;
    int i = p >> 2, hh = p & 3;
    float ei = esl[g*64 + p];
    float pv[16]; float mx = -1e30f;
    #pragma unroll
    for (int j = 0; j < 16; j++) {
      float e = ei + edl[g*64 + j*4 + hh];
      e = (e < 0.0f) ? 0.2f*e : e;
      pv[j] = e; mx = fmaxf(mx, e);
    }
    float sum = 0.0f;
    #pragma unroll
    for (int j = 0; j < 16; j++) { float pe = __expf(pv[j] - mx); pv[j] = pe; sum += pe; }
    float inv = 1.0f/sum;
    u16* ap = &al[((g*4 + hh)*16 + i)*16];
    #pragma unroll
    for (int j = 0; j < 16; j++) ap[j] = f2h(pv[j]*inv);
  }
  __syncthreads();
  int rloc = tid >> 1;
  int gg = rloc >> 4, ii = rloc & 15;
  int half = tid & 1;
  float o[64];
  #pragma unroll
  for (int hhh = 0; hhh < 2; hhh++) {
    int hh = half*2 + hhh;
    const u16* ap = &al[((gg*4 + hh)*16 + ii)*16];
    f16x8 a0 = *(const f16x8*)&ap[0];
    f16x8 a1 = *(const f16x8*)&ap[8];
    float aw[16];
    #pragma unroll
    for (int j = 0; j < 8; j++) { aw[j] = (float)a0[j]; aw[8 + j] = (float)a1[j]; }
    #pragma unroll
    for (int dd = 0; dd < 32; dd++) {
      int d = hh*32 + dd;
      float acc = 0.0f;
      #pragma unroll
      for (int j = 0; j < 16; j++) acc += aw[j]*hb[(gg*16 + j)*129 + d];
      o[hhh*32 + dd] = fmaxf(acc, 0.0f);
    }
  }
  float s = 0.0f, sq = 0.0f;
  #pragma unroll
  for (int k = 0; k < 64; k++) { s += o[k]; sq += o[k]*o[k]; }
  s  += __shfl_xor(s, 1);
  sq += __shfl_xor(sq, 1);
  float mean = s*(1.0f/128.0f);
  float var  = sq*(1.0f/128.0f) - mean*mean;
  float rstd = rsqrtf(var + 1e-5f);
  f16* orow = gout + (rowbase + rloc)*128 + half*64;
  #pragma unroll
  for (int k = 0; k < 64; k++) {
    int d = half*64 + k;
    orow[k] = (f16)((o[k] - mean)*rstd*gng[d] + gnb[d]);
  }
}

// ---------------------------------------------------------------------------
// MFMA GEMM: C[M,N](f16) = A[M,K](f16) @ W[N,K](f32)^T + bias1(+bias2).
// 128x128 tile, BK=64, 256 threads (2x2 waves of 64x64).  XOR-swizzled LDS
// (slot ^= row&7 on 16B slots -> 2-way conflicts only).  W converted f32->f16
// during reg-staging.  Requires M%128==N%128==K%64==0.
// ---------------------------------------------------------------------------
__global__ __launch_bounds__(256) void k_gemm_mfma(
    const f16* __restrict__ A, const float* __restrict__ W,
    const float* __restrict__ bias1, const float* __restrict__ bias2,
    f16* __restrict__ C, int M, int N, int K) {
  __shared__ __align__(16) u16 As[128*64];
  __shared__ __align__(16) u16 Bs[128*64];
  int tid = threadIdx.x;
  int wave = tid >> 6, lane = tid & 63;
  int wm = wave >> 1, wn = wave & 1;
  int lr = lane & 15, lg = lane >> 4;
  int m0 = blockIdx.x << 7, n0 = blockIdx.y << 7;
  f32x4 acc[4][4];
  #pragma unroll
  for (int mi = 0; mi < 4; mi++)
    #pragma unroll
    for (int ni = 0; ni < 4; ni++)
      acc[mi][ni] = (f32x4){0.0f, 0.0f, 0.0f, 0.0f};
  // per-thread staging geometry: chunk cc = it*256+tid; row=cc>>3, slot=cc&7
  for (int k0 = 0; k0 < K; k0 += 64) {
    uint4  a_st[4];
    float4 b_st[4][2];
    #pragma unroll
    for (int it = 0; it < 4; it++) {
      int cc = it*256 + tid;
      int r = cc >> 3, s = cc & 7;
      int kk = k0 + (((s ^ (r & 7))) << 3);
      a_st[it] = *(const uint4*)((const u16*)A + (size_t)(m0 + r)*K + kk);
      const float* wp = W + (size_t)(n0 + r)*K + kk;
      b_st[it][0] = *(const float4*)wp;
      b_st[it][1] = *(const float4*)(wp + 4);
    }
    __syncthreads();
    #pragma unroll
    for (int it = 0; it < 4; it++) {
      int cc = it*256 + tid;
      *(uint4*)&As[cc*8] = a_st[it];
      union { uint4 u; f16 h[8]; } bb;
      float4 x = b_st[it][0], y = b_st[it][1];
      bb.h[0] = (f16)x.x; bb.h[1] = (f16)x.y; bb.h[2] = (f16)x.z; bb.h[3] = (f16)x.w;
      bb.h[4] = (f16)y.x; bb.h[5] = (f16)y.y; bb.h[6] = (f16)y.z; bb.h[7] = (f16)y.w;
      *(uint4*)&Bs[cc*8] = bb.u;
    }
    __syncthreads();
    #pragma unroll
    for (int ks = 0; ks < 2; ks++) {
      f16x8 af[4], bf[4];
      #pragma unroll
      for (int mi = 0; mi < 4; mi++) {
        int row = wm*64 + mi*16 + lr;
        int slot = (ks*4 + lg) ^ (row & 7);
        af[mi] = *(const f16x8*)&As[row*64 + slot*8];
      }
      #pragma unroll
      for (int ni = 0; ni < 4; ni++) {
        int row = wn*64 + ni*16 + lr;
        int slot = (ks*4 + lg) ^ (row & 7);
        bf[ni] = *(const f16x8*)&Bs[row*64 + slot*8];
      }
      #pragma unroll
      for (int mi = 0; mi < 4; mi++)
        #pragma unroll
        for (int ni = 0; ni < 4; ni++)
          acc[mi][ni] = __builtin_amdgcn_mfma_f32_16x16x32_f16(af[mi], bf[ni], acc[mi][ni], 0, 0, 0);
    }
  }
  #pragma unroll
  for (int ni = 0; ni < 4; ni++) {
    int coln = n0 + wn*64 + ni*16 + lr;
    float bv = bias1[coln];
    if (bias2) bv += bias2[coln];
    #pragma unroll
    for (int mi = 0; mi < 4; mi++) {
      int rowm = m0 + wm*64 + mi*16 + lg*4;
      #pragma unroll
      for (int q = 0; q < 4; q++)
        C[(size_t)(rowm + q)*N + coln] = (f16)(acc[mi][ni][q] + bv);
    }
  }
}

// ---------------------------------------------------------------------------
// LSTM recurrence, both dirs.  One block per (batch,dir), 512 threads (one
// per gate column).  whh row (f32) packed to f16 pairs in 64 u32 registers.
// pre: (B,128,512) f16 per dir.  hout: (B,128,256) f16, dir picks half.
// ---------------------------------------------------------------------------
__global__ __launch_bounds__(512) void k_lstm(
    const f16* __restrict__ pre_f, const f16* __restrict__ pre_b,
    const float* __restrict__ whh_f, const float* __restrict__ whh_b,
    f16* __restrict__ hout) {
  __shared__ float hl[128];
  __shared__ float gl[512];
  int dir = blockIdx.x & 1, b = blockIdx.x >> 1, tid = threadIdx.x;
  const f16* pre = dir ? pre_b : pre_f;
  const float* wrow = (dir ? whh_b : whh_f) + (size_t)tid*128;
  u32 wreg[64];
  #pragma unroll
  for (int q = 0; q < 64; q++) {
    float2 wv = *(const float2*)&wrow[q << 1];
    wreg[q] = (u32)f2h(wv.x) | ((u32)f2h(wv.y) << 16);
  }
  if (tid < 128) hl[tid] = 0.0f;
  float c = 0.0f;
  __syncthreads();
  for (int s = 0; s < 128; s++) {
    int t = dir ? (127 - s) : s;
    float acc = (float)pre[((size_t)b*128 + t)*512 + tid];
    #pragma unroll
    for (int q = 0; q < 64; q++) {
      u32 wv = wreg[q];
      float2 hv = *(const float2*)&hl[q << 1];
      acc += h2fu((u16)wv)*hv.x + h2fu((u16)(wv >> 16))*hv.y;
    }
    gl[tid] = acc;
    __syncthreads();
    if (tid < 128) {
      float iv = gl[tid], fv = gl[128 + tid], gv = gl[256 + tid], ov = gl[384 + tid];
      c = sigmf(fv)*c + sigmf(iv)*tanhfast(gv);
      float hv = sigmf(ov)*tanhfast(c);
      hl[tid] = hv;
      hout[((size_t)b*128 + t)*256 + (dir << 7) + tid] = (f16)hv;
    }
    __syncthreads();
  }
}

// ---------------------------------------------------------------------------
// MHA core: one block per (batch, head).  T=128, hd=64, scale=1/8.
// qkv: (32768,768) f16 ; o: (32768,256) f16 head-concat.
// ---------------------------------------------------------------------------
__global__ __launch_bounds__(256) void k_mha(const f16* __restrict__ qkv, f16* __restrict__ o) {
  __shared__ float ql[128*66];
  __shared__ float kl[128*66];
  __shared__ u16   sl[128*132];    // exp(score-max) in f16 bits
  __shared__ float invl[128];
  int b = blockIdx.x, h = blockIdx.y, tid = threadIdx.x;
  const f16* base = qkv + (size_t)b*98304 + h*64;
  for (int i = tid; i < 8192; i += 256) {
    int t = i >> 6, d = i & 63;
    ql[t*66 + d] = (float)base[t*768 + d];
    kl[t*66 + d] = (float)base[t*768 + 256 + d];
  }
  __syncthreads();
  int i = tid >> 1, jh = (tid & 1) << 6;
  const float* qp = &ql[i*66];
  float mx = -1e30f;
  for (int j = 0; j < 64; j++) {
    const float* kp = &kl[(jh + j)*66];
    float acc = 0.0f;
    #pragma unroll 8
    for (int d = 0; d < 64; d += 2) {
      float2 qv = *(const float2*)&qp[d];
      float2 kv = *(const float2*)&kp[d];
      acc += qv.x*kv.x + qv.y*kv.y;
    }
    acc *= 0.125f;
    sl[i*132 + jh + j] = f2h(acc);
    mx = fmaxf(mx, acc);
  }
  mx = fmaxf(mx, __shfl_xor(mx, 1));
  float sum = 0.0f;
  u16* sp = &sl[i*132 + jh];
  for (int j = 0; j < 64; j++) {
    float e = __expf(h2fu(sp[j]) - mx);
    sp[j] = f2h(e);
    sum += e;
  }
  sum += __shfl_xor(sum, 1);
  if ((tid & 1) == 0) invl[i] = 1.0f/sum;
  __syncthreads();
  for (int i2 = tid; i2 < 8192; i2 += 256) {     // V overwrites ql
    int t = i2 >> 6, d = i2 & 63;
    ql[t*66 + d] = (float)base[t*768 + 512 + d];
  }
  __syncthreads();
  for (int it = 0; it < 32; it++) {
    int idx = it*256 + tid;
    int oi = idx >> 6, d = idx & 63;
    const u16* pp = &sl[oi*132];
    float acc = 0.0f;
    #pragma unroll 16
    for (int j = 0; j < 128; j++) acc += h2fu(pp[j])*ql[j*66 + d];
    o[((size_t)b*128 + oi)*256 + h*64 + d] = (f16)(acc*invl[oi]);
  }
}

// ---------------------------------------------------------------------------
// att = LayerNorm(mha_out + lstm_out), width 256.  One wave per row.
// ---------------------------------------------------------------------------
__global__ __launch_bounds__(256) void k_lnres(
    const f16* __restrict__ a, const f16* __restrict__ r,
    const float* __restrict__ g, const float* __restrict__ bb, f16* __restrict__ out) {
  int row = blockIdx.x*4 + (threadIdx.x >> 6);
  int lane = threadIdx.x & 63;
  const f16* ar = a + (size_t)row*256 + lane*4;
  const f16* rr = r + (size_t)row*256 + lane*4;
  float v0 = (float)ar[0] + (float)rr[0];
  float v1 = (float)ar[1] + (float)rr[1];
  float v2 = (float)ar[2] + (float)rr[2];
  float v3 = (float)ar[3] + (float)rr[3];
  float s = v0 + v1 + v2 + v3;
  float q = v0*v0 + v1*v1 + v2*v2 + v3*v3;
  #pragma unroll
  for (int off = 32; off; off >>= 1) { s += __shfl_xor(s, off); q += __shfl_xor(q, off); }
  float mean = s*(1.0f/256.0f);
  float var  = q*(1.0f/256.0f) - mean*mean;
  float rstd = rsqrtf(var + 1e-5f);
  int d0 = lane*4;
  f16* op = out + (size_t)row*256 + d0;
  op[0] = (f16)((v0 - mean)*rstd*g[d0+0] + bb[d0+0]);
  op[1] = (f16)((v1 - mean)*rstd*g[d0+1] + bb[d0+1]);
  op[2] = (f16)((v2 - mean)*rstd*g[d0+2] + bb[d0+2]);
  op[3] = (f16)((v3 - mean)*rstd*g[d0+3] + bb[d0+3]);
}

// ---------------------------------------------------------------------------
// mean/max pool over T, LayerNorm(512), cls1+ReLU, cls2.  One block per batch.
// ---------------------------------------------------------------------------
__global__ __launch_bounds__(512) void k_pool_cls(
    const f16* __restrict__ att, const float* __restrict__ png, const float* __restrict__ pnb,
    const float* __restrict__ w1, const float* __restrict__ b1,
    const float* __restrict__ w2, const float* __restrict__ b2, float* __restrict__ out) {
  __shared__ float pl[512];
  __shared__ float redS[8], redQ[8];
  __shared__ float mrv[2];
  __shared__ float hl[128];
  int b = blockIdx.x, tid = threadIdx.x;
  if (tid < 256) {
    const f16* ar = att + (size_t)b*32768 + tid;
    float s = 0.0f, mx = -1e30f;
    for (int t = 0; t < 128; t++) { float v = (float)ar[t*256]; s += v; mx = fmaxf(mx, v); }
    pl[tid] = s*(1.0f/128.0f);
    pl[256 + tid] = mx;
  }
  __syncthreads();
  float v = pl[tid];
  float s = v, q = v*v;
  #pragma unroll
  for (int off = 32; off; off >>= 1) { s += __shfl_xor(s, off); q += __shfl_xor(q, off); }
  if ((tid & 63) == 0) { redS[tid >> 6] = s; redQ[tid >> 6] = q; }
  __syncthreads();
  if (tid == 0) {
    float S = 0.0f, Q = 0.0f;
    #pragma unroll
    for (int w = 0; w < 8; w++) { S += redS[w]; Q += redQ[w]; }
    float mean = S*(1.0f/512.0f);
    float var  = Q*(1.0f/512.0f) - mean*mean;
    mrv[0] = mean; mrv[1] = rsqrtf(var + 1e-5f);
  }
  __syncthreads();
  pl[tid] = (v - mrv[0])*mrv[1]*png[tid] + pnb[tid];
  __syncthreads();
  if (tid < 128) {
    float acc = b1[tid];
    const float* wrp = w1 + (size_t)tid*512;
    for (int d = 0; d < 512; d++) acc += pl[d]*wrp[d];
    hl[tid] = fmaxf(acc, 0.0f)*w2[tid];
  }
  __syncthreads();
  if (tid < 64) {
    float rsum = hl[tid] + hl[tid + 64];
    #pragma unroll
    for (int off = 32; off; off >>= 1) rsum += __shfl_xor(rsum, off);
    if (tid == 0) out[b] = rsum + b2[0];
  }
}

// ---------------------------------------------------------------------------
extern "C" void kernel_launch(void* const* d_in, const int* in_sizes, int n_in,
                              void* d_out, int out_size, void* d_ws, size_t ws_size,
                              hipStream_t stream) {
  (void)in_sizes; (void)n_in; (void)out_size;
  if (ws_size < (size_t)192*1024*1024) return;   // >=192 MiB proven present
  const float* IN[47];
  for (int i = 0; i < 47; i++) IN[i] = (const float*)d_in[i];
  char* W8 = (char*)d_ws;
  // liveness-packed layout (MiB offsets), peak 192 MiB:
  f16* feat     = (f16*)(W8 + ((size_t)0  << 20));  // [0,64)   dead after GAT1
  f16* g        = (f16*)(W8 + ((size_t)64 << 20));  // [64,192) dead after pre GEMMs
  f16* pre_f    = (f16*)(W8 + ((size_t)0  << 20));  // [0,32)
  f16* pre_b    = (f16*)(W8 + ((size_t)32 << 20));  // [32,64)
  f16* h1       = (f16*)(W8 + ((size_t)64 << 20));  // [64,80)
  f16* lstm_out = (f16*)(W8 + ((size_t)80 << 20));  // [80,96)  live till lnres
  f16* qkv      = (f16*)(W8 + ((size_t)96 << 20));  // [96,144)
  f16* o_flat   = (f16*)(W8 + ((size_t)0  << 20));  // [0,16)
  f16* mo       = (f16*)(W8 + ((size_t)16 << 20));  // [16,32)
  f16* att      = (f16*)(W8 + ((size_t)32 << 20));  // [32,48)

  k_conv<<<4096, 256, 0, stream>>>(IN[0], IN[1], IN[2], IN[3], IN[4],
                                   IN[5], IN[6], IN[7], IN[8], feat);
  k_gat_mfma<64><<<4096, 256, 0, stream>>>(feat, IN[9], IN[10], IN[11], IN[12], IN[13], g);
  k_gat_mfma<128><<<4096, 256, 0, stream>>>(g, IN[14], IN[15], IN[16], IN[17], IN[18], g);
  k_gemm_mfma<<<dim3(256, 4), 256, 0, stream>>>(g, IN[19], IN[21], IN[22], pre_f, 32768, 512, 2048);
  k_gemm_mfma<<<dim3(256, 4), 256, 0, stream>>>(g, IN[23], IN[25], IN[26], pre_b, 32768, 512, 2048);
  k_lstm<<<512, 512, 0, stream>>>(pre_f, pre_b, IN[20], IN[24], h1);
  k_gemm_mfma<<<dim3(256, 4), 256, 0, stream>>>(h1, IN[27], IN[29], IN[30], pre_f, 32768, 512, 256);
  k_gemm_mfma<<<dim3(256, 4), 256, 0, stream>>>(h1, IN[31], IN[33], IN[34], pre_b, 32768, 512, 256);
  k_lstm<<<512, 512, 0, stream>>>(pre_f, pre_b, IN[28], IN[32], lstm_out);
  k_gemm_mfma<<<dim3(256, 6), 256, 0, stream>>>(lstm_out, IN[35], IN[36], nullptr, qkv, 32768, 768, 256);
  k_mha<<<dim3(256, 4), 256, 0, stream>>>(qkv, o_flat);
  k_gemm_mfma<<<dim3(256, 2), 256, 0, stream>>>(o_flat, IN[37], IN[38], nullptr, mo, 32768, 256, 256);
  k_lnres<<<8192, 256, 0, stream>>>(mo, lstm_out, IN[39], IN[40], att);
  k_pool_cls<<<256, 512, 0, stream>>>(att, IN[41], IN[42], IN[43], IN[44], IN[45], IN[46],
                                      (float*)d_out);
}

// Round 6
// 2491.934 us; speedup vs baseline: 2.3245x; 1.1454x over previous
//
#include <hip/hip_runtime.h>
#include <hip/hip_bf16.h>

typedef _Float16 f16;
typedef unsigned short u16;
typedef unsigned int   u32;
typedef __attribute__((ext_vector_type(8))) _Float16 f16x8;
typedef __attribute__((ext_vector_type(4))) float    f32x4;

__device__ __forceinline__ float h2fu(u16 u) { union { u16 s; f16 h; } t; t.s = u; return (float)t.h; }
__device__ __forceinline__ u16   f2h(float f) { union { u16 s; f16 h; } t; t.h = (f16)f; return t.s; }
__device__ __forceinline__ float geluf(float u) { return 0.5f*u*(1.0f + erff(u*0.70710678118654752f)); }
__device__ __forceinline__ float sigmf(float x) { return 1.0f/(1.0f + __expf(-x)); }
__device__ __forceinline__ float tanhfast(float x) { return 1.0f - 2.0f/(__expf(2.0f*x) + 1.0f); }

// ---------------------------------------------------------------------------
// Fused conv1(1->32,k7,p3)+bn+gelu -> conv2(32->64,k5,s2,p2)+bn+gelu.
// One block per input row r=(b*16+n).  Writes feat[(b*128+t2)*16+n][64] f16.
// LDS ~40 KiB (f16 yl/wt) -> 4 blocks/CU.  Sliding-window conv2 inner.
// ---------------------------------------------------------------------------
__global__ __launch_bounds__(256) void k_conv(
    const float* __restrict__ x,
    const float* __restrict__ w1, const float* __restrict__ cb1v,
    const float* __restrict__ g1v, const float* __restrict__ be1v,
    const float* __restrict__ w2, const float* __restrict__ cb2v,
    const float* __restrict__ g2v, const float* __restrict__ be2v,
    f16* __restrict__ feat) {
  __shared__ float xs[262];
  __shared__ __align__(16) u16 ylh[32*260];   // conv1 out f16, padded +-2, data at +2
  __shared__ __align__(16) u16 wth[160*64];   // wth[(ic*5+kk)*64 + oc] f16
  __shared__ float w1l[224];
  __shared__ float cb1[32], sc1[32], sb1[32];
  __shared__ float cb2[64], sc2[64], sb2[64];
  int r = blockIdx.x, tid = threadIdx.x;
  int bb = r >> 4, n = r & 15;
  for (int i = tid; i < 262; i += 256) {
    int p = i - 3;
    xs[i] = (p >= 0 && p < 256) ? x[(size_t)r*256 + p] : 0.0f;
  }
  if (tid < 224) {
    w1l[tid] = w1[tid];
  } else {
    int oc = tid - 224;
    cb1[oc] = cb1v[oc];
    sc1[oc] = g1v[oc] * rsqrtf(1.0f + 1e-5f);
    sb1[oc] = be1v[oc];
  }
  // coalesced LDS writes: lane = oc (consecutive u16), strided global read (L2)
  for (int i = tid; i < 10240; i += 256) {
    int rest = i >> 6, oc = i & 63;
    wth[rest*64 + oc] = f2h(w2[oc*160 + rest]);
  }
  if (tid < 64) {
    cb2[tid] = cb2v[tid];
    sc2[tid] = g2v[tid] * rsqrtf(1.0f + 1e-5f);
    sb2[tid] = be2v[tid];
  }
  for (int i = tid; i < 128; i += 256) {       // zero pads of ylh
    int ic = i >> 2, z = i & 3;
    ylh[ic*260 + (z < 2 ? z : 256 + z)] = 0;
  }
  __syncthreads();
  // stage 1: conv1 at position t=tid for all 32 oc
  float xv[7];
  #pragma unroll
  for (int k = 0; k < 7; k++) xv[k] = xs[tid + k];
  for (int oc = 0; oc < 32; oc++) {
    float acc = cb1[oc];
    #pragma unroll
    for (int k = 0; k < 7; k++) acc += w1l[oc*7 + k]*xv[k];
    float u = acc*sc1[oc] + sb1[oc];
    ylh[oc*260 + 2 + tid] = f2h(geluf(u));
  }
  __syncthreads();
  // stage 2: conv2, sliding window over consecutive t2 (t2 = t4*32 + q)
  int oc = tid & 63, t4 = tid >> 6;
  float acc[32];
  #pragma unroll
  for (int q = 0; q < 32; q++) acc[q] = cb2[oc];
  for (int ic = 0; ic < 32; ic++) {
    const u16* wp = &wth[(ic*5)*64 + oc];
    float w0 = h2fu(wp[0]),  ww1 = h2fu(wp[64]),  ww2 = h2fu(wp[128]),
          ww3 = h2fu(wp[192]), ww4 = h2fu(wp[256]);
    const u16* yy = &ylh[ic*260];
    int base = t4*64;                      // wave-uniform -> broadcast reads
    u32 p0 = *(const u32*)&yy[base];
    u32 p1 = *(const u32*)&yy[base + 2];
    float y0 = h2fu((u16)p0), y1 = h2fu((u16)(p0 >> 16));
    float y2 = h2fu((u16)p1), y3 = h2fu((u16)(p1 >> 16));
    #pragma unroll
    for (int q = 0; q < 32; q++) {
      u32 p2 = *(const u32*)&yy[base + 2*q + 4];
      float y4 = h2fu((u16)p2), y5 = h2fu((u16)(p2 >> 16));
      acc[q] += w0*y0 + ww1*y1 + ww2*y2 + ww3*y3 + ww4*y4;
      y0 = y2; y1 = y3; y2 = y4; y3 = y5;
    }
  }
  #pragma unroll
  for (int q = 0; q < 32; q++) {
    int t2 = t4*32 + q;
    float u = acc[q]*sc2[oc] + sb2[oc];
    feat[(((size_t)bb*128 + t2)*16 + n)*64 + oc] = (f16)geluf(u);
  }
}

// ---------------------------------------------------------------------------
// GAT layer (+ReLU +LayerNorm) via MFMA.  One block = 8 graphs (128 rows),
// 256 threads (4 waves).  (unchanged — validated)
// ---------------------------------------------------------------------------
template<int F>
__global__ __launch_bounds__(256) void k_gat_mfma(
    const f16* __restrict__ xin, const float* __restrict__ W,
    const float* __restrict__ asrc, const float* __restrict__ adst,
    const float* __restrict__ gng, const float* __restrict__ gnb,
    f16* __restrict__ gout) {
  constexpr int XP = F + 8;
  __shared__ __align__(16) u16 xa[128*XP];
  __shared__ __align__(16) u16 wt[128*XP];
  __shared__ float hb[128*129];
  __shared__ float esl[512], edl[512];
  __shared__ float wsv[128], wdv[128];
  int tid = threadIdx.x;
  size_t rowbase = (size_t)blockIdx.x*128;
  const u32* xg = (const u32*)(xin + rowbase*F);
  for (int i = tid; i < 128*F/2; i += 256) {
    u32 v = xg[i];
    int r = (2*i)/F, k = (2*i)%F;
    *(u32*)&xa[r*XP + k] = v;
  }
  for (int i = tid; i < F*128; i += 256) {
    int k = i >> 7, c = i & 127;
    wt[c*XP + k] = f2h(W[i]);
  }
  if (tid < 128) { wsv[tid] = asrc[tid]; wdv[tid] = adst[tid]; }
  __syncthreads();
  int wave = tid >> 6, lane = tid & 63;
  int lr = lane & 15, lg = lane >> 4;
  #pragma unroll
  for (int mi = 0; mi < 2; mi++) {
    int mt = wave*2 + mi;
    f16x8 af[F/32];
    #pragma unroll
    for (int kb = 0; kb < F/32; kb++)
      af[kb] = *(const f16x8*)&xa[(mt*16 + lr)*XP + kb*32 + lg*8];
    #pragma unroll
    for (int nt = 0; nt < 8; nt++) {
      f32x4 acc = {0.0f, 0.0f, 0.0f, 0.0f};
      #pragma unroll
      for (int kb = 0; kb < F/32; kb++) {
        f16x8 bf = *(const f16x8*)&wt[(nt*16 + lr)*XP + kb*32 + lg*8];
        acc = __builtin_amdgcn_mfma_f32_16x16x32_f16(af[kb], bf, acc, 0, 0, 0);
      }
      #pragma unroll
      for (int q = 0; q < 4; q++)
        hb[(mt*16 + lg*4 + q)*129 + nt*16 + lr] = acc[q];
    }
  }
  __syncthreads();
  int g = tid >> 5, l32 = tid & 31;
  #pragma unroll
  for (int q = 0; q < 2; q++) {
    int p = l32 + 32*q;
    int n = p >> 2, hh = p & 3;
    const float* hp  = &hb[(g*16 + n)*129 + hh*32];
    const float* wsp = &wsv[hh*32];
    const float* wdp = &wdv[hh*32];
    float es = 0.0f, ed = 0.0f;
    #pragma unroll
    for (int d = 0; d < 32; d++) { float hv = hp[d]; es += hv*wsp[d]; ed += hv*wdp[d]; }
    esl[g*64 + p] = es; edl[g*64 + p] = ed;
  }
  __syncthreads();
  u16* al = xa;
  #pragma unroll
  for (int q = 0; q < 2; q++) {
    int p = l32 + 32*q;
    int i = p >> 2, hh = p & 3;
    float ei = esl[g*64 + p];
    float pv[16]; float mx = -1e30f;
    #pragma unroll
    for (int j = 0; j < 16; j++) {
      float e = ei + edl[g*64 + j*4 + hh];
      e = (e < 0.0f) ? 0.2f*e : e;
      pv[j] = e; mx = fmaxf(mx, e);
    }
    float sum = 0.0f;
    #pragma unroll
    for (int j = 0; j < 16; j++) { float pe = __expf(pv[j] - mx); pv[j] = pe; sum += pe; }
    float inv = 1.0f/sum;
    u16* ap = &al[((g*4 + hh)*16 + i)*16];
    #pragma unroll
    for (int j = 0; j < 16; j++) ap[j] = f2h(pv[j]*inv);
  }
  __syncthreads();
  int rloc = tid >> 1;
  int gg = rloc >> 4, ii = rloc & 15;
  int half = tid & 1;
  float o[64];
  #pragma unroll
  for (int hhh = 0; hhh < 2; hhh++) {
    int hh = half*2 + hhh;
    const u16* ap = &al[((gg*4 + hh)*16 + ii)*16];
    f16x8 a0 = *(const f16x8*)&ap[0];
    f16x8 a1 = *(const f16x8*)&ap[8];
    float aw[16];
    #pragma unroll
    for (int j = 0; j < 8; j++) { aw[j] = (float)a0[j]; aw[8 + j] = (float)a1[j]; }
    #pragma unroll
    for (int dd = 0; dd < 32; dd++) {
      int d = hh*32 + dd;
      float acc = 0.0f;
      #pragma unroll
      for (int j = 0; j < 16; j++) acc += aw[j]*hb[(gg*16 + j)*129 + d];
      o[hhh*32 + dd] = fmaxf(acc, 0.0f);
    }
  }
  float s = 0.0f, sq = 0.0f;
  #pragma unroll
  for (int k = 0; k < 64; k++) { s += o[k]; sq += o[k]*o[k]; }
  s  += __shfl_xor(s, 1);
  sq += __shfl_xor(sq, 1);
  float mean = s*(1.0f/128.0f);
  float var  = sq*(1.0f/128.0f) - mean*mean;
  float rstd = rsqrtf(var + 1e-5f);
  f16* orow = gout + (rowbase + rloc)*128 + half*64;
  #pragma unroll
  for (int k = 0; k < 64; k++) {
    int d = half*64 + k;
    orow[k] = (f16)((o[k] - mean)*rstd*gng[d] + gnb[d]);
  }
}

// ---------------------------------------------------------------------------
// MFMA GEMM (unchanged — validated): C[M,N](f16) = A@W^T + bias1(+bias2).
// ---------------------------------------------------------------------------
__global__ __launch_bounds__(256) void k_gemm_mfma(
    const f16* __restrict__ A, const float* __restrict__ W,
    const float* __restrict__ bias1, const float* __restrict__ bias2,
    f16* __restrict__ C, int M, int N, int K) {
  __shared__ __align__(16) u16 As[128*64];
  __shared__ __align__(16) u16 Bs[128*64];
  int tid = threadIdx.x;
  int wave = tid >> 6, lane = tid & 63;
  int wm = wave >> 1, wn = wave & 1;
  int lr = lane & 15, lg = lane >> 4;
  int m0 = blockIdx.x << 7, n0 = blockIdx.y << 7;
  f32x4 acc[4][4];
  #pragma unroll
  for (int mi = 0; mi < 4; mi++)
    #pragma unroll
    for (int ni = 0; ni < 4; ni++)
      acc[mi][ni] = (f32x4){0.0f, 0.0f, 0.0f, 0.0f};
  for (int k0 = 0; k0 < K; k0 += 64) {
    uint4  a_st[4];
    float4 b_st[4][2];
    #pragma unroll
    for (int it = 0; it < 4; it++) {
      int cc = it*256 + tid;
      int r = cc >> 3, s = cc & 7;
      int kk = k0 + (((s ^ (r & 7))) << 3);
      a_st[it] = *(const uint4*)((const u16*)A + (size_t)(m0 + r)*K + kk);
      const float* wp = W + (size_t)(n0 + r)*K + kk;
      b_st[it][0] = *(const float4*)wp;
      b_st[it][1] = *(const float4*)(wp + 4);
    }
    __syncthreads();
    #pragma unroll
    for (int it = 0; it < 4; it++) {
      int cc = it*256 + tid;
      *(uint4*)&As[cc*8] = a_st[it];
      union { uint4 u; f16 h[8]; } bb;
      float4 x = b_st[it][0], y = b_st[it][1];
      bb.h[0] = (f16)x.x; bb.h[1] = (f16)x.y; bb.h[2] = (f16)x.z; bb.h[3] = (f16)x.w;
      bb.h[4] = (f16)y.x; bb.h[5] = (f16)y.y; bb.h[6] = (f16)y.z; bb.h[7] = (f16)y.w;
      *(uint4*)&Bs[cc*8] = bb.u;
    }
    __syncthreads();
    #pragma unroll
    for (int ks = 0; ks < 2; ks++) {
      f16x8 af[4], bf[4];
      #pragma unroll
      for (int mi = 0; mi < 4; mi++) {
        int row = wm*64 + mi*16 + lr;
        int slot = (ks*4 + lg) ^ (row & 7);
        af[mi] = *(const f16x8*)&As[row*64 + slot*8];
      }
      #pragma unroll
      for (int ni = 0; ni < 4; ni++) {
        int row = wn*64 + ni*16 + lr;
        int slot = (ks*4 + lg) ^ (row & 7);
        bf[ni] = *(const f16x8*)&Bs[row*64 + slot*8];
      }
      #pragma unroll
      for (int mi = 0; mi < 4; mi++)
        #pragma unroll
        for (int ni = 0; ni < 4; ni++)
          acc[mi][ni] = __builtin_amdgcn_mfma_f32_16x16x32_f16(af[mi], bf[ni], acc[mi][ni], 0, 0, 0);
    }
  }
  #pragma unroll
  for (int ni = 0; ni < 4; ni++) {
    int coln = n0 + wn*64 + ni*16 + lr;
    float bv = bias1[coln];
    if (bias2) bv += bias2[coln];
    #pragma unroll
    for (int mi = 0; mi < 4; mi++) {
      int rowm = m0 + wm*64 + mi*16 + lg*4;
      #pragma unroll
      for (int q = 0; q < 4; q++)
        C[(size_t)(rowm + q)*N + coln] = (f16)(acc[mi][ni][q] + bv);
    }
  }
}

// ---------------------------------------------------------------------------
// LSTM recurrence, both dirs.  One block per (batch,dir), 512 threads (one
// per gate column).  4-way split accumulators (break FMA dependency chain)
// + next-step pre prefetch (hide global latency under the dot+barrier).
// ---------------------------------------------------------------------------
__global__ __launch_bounds__(512) void k_lstm(
    const f16* __restrict__ pre_f, const f16* __restrict__ pre_b,
    const float* __restrict__ whh_f, const float* __restrict__ whh_b,
    f16* __restrict__ hout) {
  __shared__ float hl[128];
  __shared__ float gl[512];
  int dir = blockIdx.x & 1, b = blockIdx.x >> 1, tid = threadIdx.x;
  const f16* pre = dir ? pre_b : pre_f;
  const float* wrow = (dir ? whh_b : whh_f) + (size_t)tid*128;
  u32 wreg[64];
  #pragma unroll
  for (int q = 0; q < 64; q++) {
    float2 wv = *(const float2*)&wrow[q << 1];
    wreg[q] = (u32)f2h(wv.x) | ((u32)f2h(wv.y) << 16);
  }
  if (tid < 128) hl[tid] = 0.0f;
  float c = 0.0f;
  float pre_cur = (float)pre[((size_t)b*128 + (dir ? 127 : 0))*512 + tid];
  __syncthreads();
  for (int s = 0; s < 128; s++) {
    int t = dir ? (127 - s) : s;
    float pre_next = 0.0f;
    if (s < 127) {
      int tn = dir ? (126 - s) : (s + 1);
      pre_next = (float)pre[((size_t)b*128 + tn)*512 + tid];
    }
    float a0 = 0.0f, a1 = 0.0f, a2 = 0.0f, a3 = 0.0f;
    #pragma unroll
    for (int q = 0; q < 16; q++) {
      u32 w0 = wreg[q], w1v = wreg[q + 16], w2v = wreg[q + 32], w3v = wreg[q + 48];
      float2 h0 = *(const float2*)&hl[q << 1];
      float2 h1 = *(const float2*)&hl[(q + 16) << 1];
      float2 h2 = *(const float2*)&hl[(q + 32) << 1];
      float2 h3 = *(const float2*)&hl[(q + 48) << 1];
      a0 += h2fu((u16)w0)*h0.x  + h2fu((u16)(w0  >> 16))*h0.y;
      a1 += h2fu((u16)w1v)*h1.x + h2fu((u16)(w1v >> 16))*h1.y;
      a2 += h2fu((u16)w2v)*h2.x + h2fu((u16)(w2v >> 16))*h2.y;
      a3 += h2fu((u16)w3v)*h3.x + h2fu((u16)(w3v >> 16))*h3.y;
    }
    gl[tid] = pre_cur + ((a0 + a1) + (a2 + a3));
    __syncthreads();
    if (tid < 128) {
      float iv = gl[tid], fv = gl[128 + tid], gv = gl[256 + tid], ov = gl[384 + tid];
      c = sigmf(fv)*c + sigmf(iv)*tanhfast(gv);
      float hv = sigmf(ov)*tanhfast(c);
      hl[tid] = hv;
      hout[((size_t)b*128 + t)*256 + (dir << 7) + tid] = (f16)hv;
    }
    __syncthreads();
    pre_cur = pre_next;
  }
}

// ---------------------------------------------------------------------------
// MHA core: one block per (batch, head).  T=128, hd=64, scale=1/8.
// ---------------------------------------------------------------------------
__global__ __launch_bounds__(256) void k_mha(const f16* __restrict__ qkv, f16* __restrict__ o) {
  __shared__ float ql[128*66];
  __shared__ float kl[128*66];
  __shared__ u16   sl[128*132];    // exp(score-max) in f16 bits
  __shared__ float invl[128];
  int b = blockIdx.x, h = blockIdx.y, tid = threadIdx.x;
  const f16* base = qkv + (size_t)b*98304 + h*64;
  for (int i = tid; i < 8192; i += 256) {
    int t = i >> 6, d = i & 63;
    ql[t*66 + d] = (float)base[t*768 + d];
    kl[t*66 + d] = (float)base[t*768 + 256 + d];
  }
  __syncthreads();
  int i = tid >> 1, jh = (tid & 1) << 6;
  const float* qp = &ql[i*66];
  float mx = -1e30f;
  for (int j = 0; j < 64; j++) {
    const float* kp = &kl[(jh + j)*66];
    float acc = 0.0f;
    #pragma unroll 8
    for (int d = 0; d < 64; d += 2) {
      float2 qv = *(const float2*)&qp[d];
      float2 kv = *(const float2*)&kp[d];
      acc += qv.x*kv.x + qv.y*kv.y;
    }
    acc *= 0.125f;
    sl[i*132 + jh + j] = f2h(acc);
    mx = fmaxf(mx, acc);
  }
  mx = fmaxf(mx, __shfl_xor(mx, 1));
  float sum = 0.0f;
  u16* sp = &sl[i*132 + jh];
  for (int j = 0; j < 64; j++) {
    float e = __expf(h2fu(sp[j]) - mx);
    sp[j] = f2h(e);
    sum += e;
  }
  sum += __shfl_xor(sum, 1);
  if ((tid & 1) == 0) invl[i] = 1.0f/sum;
  __syncthreads();
  for (int i2 = tid; i2 < 8192; i2 += 256) {     // V overwrites ql
    int t = i2 >> 6, d = i2 & 63;
    ql[t*66 + d] = (float)base[t*768 + 512 + d];
  }
  __syncthreads();
  for (int it = 0; it < 32; it++) {
    int idx = it*256 + tid;
    int oi = idx >> 6, d = idx & 63;
    const u16* pp = &sl[oi*132];
    float acc = 0.0f;
    #pragma unroll 16
    for (int j = 0; j < 128; j++) acc += h2fu(pp[j])*ql[j*66 + d];
    o[((size_t)b*128 + oi)*256 + h*64 + d] = (f16)(acc*invl[oi]);
  }
}

// ---------------------------------------------------------------------------
// att = LayerNorm(mha_out + lstm_out), width 256.  One wave per row.
// ---------------------------------------------------------------------------
__global__ __launch_bounds__(256) void k_lnres(
    const f16* __restrict__ a, const f16* __restrict__ r,
    const float* __restrict__ g, const float* __restrict__ bb, f16* __restrict__ out) {
  int row = blockIdx.x*4 + (threadIdx.x >> 6);
  int lane = threadIdx.x & 63;
  const f16* ar = a + (size_t)row*256 + lane*4;
  const f16* rr = r + (size_t)row*256 + lane*4;
  float v0 = (float)ar[0] + (float)rr[0];
  float v1 = (float)ar[1] + (float)rr[1];
  float v2 = (float)ar[2] + (float)rr[2];
  float v3 = (float)ar[3] + (float)rr[3];
  float s = v0 + v1 + v2 + v3;
  float q = v0*v0 + v1*v1 + v2*v2 + v3*v3;
  #pragma unroll
  for (int off = 32; off; off >>= 1) { s += __shfl_xor(s, off); q += __shfl_xor(q, off); }
  float mean = s*(1.0f/256.0f);
  float var  = q*(1.0f/256.0f) - mean*mean;
  float rstd = rsqrtf(var + 1e-5f);
  int d0 = lane*4;
  f16* op = out + (size_t)row*256 + d0;
  op[0] = (f16)((v0 - mean)*rstd*g[d0+0] + bb[d0+0]);
  op[1] = (f16)((v1 - mean)*rstd*g[d0+1] + bb[d0+1]);
  op[2] = (f16)((v2 - mean)*rstd*g[d0+2] + bb[d0+2]);
  op[3] = (f16)((v3 - mean)*rstd*g[d0+3] + bb[d0+3]);
}

// ---------------------------------------------------------------------------
// mean/max pool over T, LayerNorm(512), cls1+ReLU, cls2.  One block per batch.
// ---------------------------------------------------------------------------
__global__ __launch_bounds__(512) void k_pool_cls(
    const f16* __restrict__ att, const float* __restrict__ png, const float* __restrict__ pnb,
    const float* __restrict__ w1, const float* __restrict__ b1,
    const float* __restrict__ w2, const float* __restrict__ b2, float* __restrict__ out) {
  __shared__ float pl[512];
  __shared__ float redS[8], redQ[8];
  __shared__ float mrv[2];
  __shared__ float hl[128];
  int b = blockIdx.x, tid = threadIdx.x;
  if (tid < 256) {
    const f16* ar = att + (size_t)b*32768 + tid;
    float s = 0.0f, mx = -1e30f;
    for (int t = 0; t < 128; t++) { float v = (float)ar[t*256]; s += v; mx = fmaxf(mx, v); }
    pl[tid] = s*(1.0f/128.0f);
    pl[256 + tid] = mx;
  }
  __syncthreads();
  float v = pl[tid];
  float s = v, q = v*v;
  #pragma unroll
  for (int off = 32; off; off >>= 1) { s += __shfl_xor(s, off); q += __shfl_xor(q, off); }
  if ((tid & 63) == 0) { redS[tid >> 6] = s; redQ[tid >> 6] = q; }
  __syncthreads();
  if (tid == 0) {
    float S = 0.0f, Q = 0.0f;
    #pragma unroll
    for (int w = 0; w < 8; w++) { S += redS[w]; Q += redQ[w]; }
    float mean = S*(1.0f/512.0f);
    float var  = Q*(1.0f/512.0f) - mean*mean;
    mrv[0] = mean; mrv[1] = rsqrtf(var + 1e-5f);
  }
  __syncthreads();
  pl[tid] = (v - mrv[0])*mrv[1]*png[tid] + pnb[tid];
  __syncthreads();
  if (tid < 128) {
    float acc = b1[tid];
    const float* wrp = w1 + (size_t)tid*512;
    for (int d = 0; d < 512; d++) acc += pl[d]*wrp[d];
    hl[tid] = fmaxf(acc, 0.0f)*w2[tid];
  }
  __syncthreads();
  if (tid < 64) {
    float rsum = hl[tid] + hl[tid + 64];
    #pragma unroll
    for (int off = 32; off; off >>= 1) rsum += __shfl_xor(rsum, off);
    if (tid == 0) out[b] = rsum + b2[0];
  }
}

// ---------------------------------------------------------------------------
extern "C" void kernel_launch(void* const* d_in, const int* in_sizes, int n_in,
                              void* d_out, int out_size, void* d_ws, size_t ws_size,
                              hipStream_t stream) {
  (void)in_sizes; (void)n_in; (void)out_size;
  if (ws_size < (size_t)192*1024*1024) return;   // >=192 MiB proven present
  const float* IN[47];
  for (int i = 0; i < 47; i++) IN[i] = (const float*)d_in[i];
  char* W8 = (char*)d_ws;
  f16* feat     = (f16*)(W8 + ((size_t)0  << 20));  // [0,64)   dead after GAT1
  f16* g        = (f16*)(W8 + ((size_t)64 << 20));  // [64,192) dead after pre GEMMs
  f16* pre_f    = (f16*)(W8 + ((size_t)0  << 20));  // [0,32)
  f16* pre_b    = (f16*)(W8 + ((size_t)32 << 20));  // [32,64)
  f16* h1       = (f16*)(W8 + ((size_t)64 << 20));  // [64,80)
  f16* lstm_out = (f16*)(W8 + ((size_t)80 << 20));  // [80,96)  live till lnres
  f16* qkv      = (f16*)(W8 + ((size_t)96 << 20));  // [96,144)
  f16* o_flat   = (f16*)(W8 + ((size_t)0  << 20));  // [0,16)
  f16* mo       = (f16*)(W8 + ((size_t)16 << 20));  // [16,32)
  f16* att      = (f16*)(W8 + ((size_t)32 << 20));  // [32,48)

  k_conv<<<4096, 256, 0, stream>>>(IN[0], IN[1], IN[2], IN[3], IN[4],
                                   IN[5], IN[6], IN[7], IN[8], feat);
  k_gat_mfma<64><<<4096, 256, 0, stream>>>(feat, IN[9], IN[10], IN[11], IN[12], IN[13], g);
  k_gat_mfma<128><<<4096, 256, 0, stream>>>(g, IN[14], IN[15], IN[16], IN[17], IN[18], g);
  k_gemm_mfma<<<dim3(256, 4), 256, 0, stream>>>(g, IN[19], IN[21], IN[22], pre_f, 32768, 512, 2048);
  k_gemm_mfma<<<dim3(256, 4), 256, 0, stream>>>(g, IN[23], IN[25], IN[26], pre_b, 32768, 512, 2048);
  k_lstm<<<512, 512, 0, stream>>>(pre_f, pre_b, IN[20], IN[24], h1);
  k_gemm_mfma<<<dim3(256, 4), 256, 0, stream>>>(h1, IN[27], IN[29], IN[30], pre_f, 32768, 512, 256);
  k_gemm_mfma<<<dim3(256, 4), 256, 0, stream>>>(h1, IN[31], IN[33], IN[34], pre_b, 32768, 512, 256);
  k_lstm<<<512, 512, 0, stream>>>(pre_f, pre_b, IN[28], IN[32], lstm_out);
  k_gemm_mfma<<<dim3(256, 6), 256, 0, stream>>>(lstm_out, IN[35], IN[36], nullptr, qkv, 32768, 768, 256);
  k_mha<<<dim3(256, 4), 256, 0, stream>>>(qkv, o_flat);
  k_gemm_mfma<<<dim3(256, 2), 256, 0, stream>>>(o_flat, IN[37], IN[38], nullptr, mo, 32768, 256, 256);
  k_lnres<<<8192, 256, 0, stream>>>(mo, lstm_out, IN[39], IN[40], att);
  k_pool_cls<<<256, 512, 0, stream>>>(att, IN[41], IN[42], IN[43], IN[44], IN[45], IN[46],
                                      (float*)d_out);
}

// Round 7
// 2221.104 us; speedup vs baseline: 2.6079x; 1.1219x over previous
//
#include <hip/hip_runtime.h>
#include <hip/hip_bf16.h>

typedef _Float16 f16;
typedef unsigned short u16;
typedef unsigned int   u32;
typedef __attribute__((ext_vector_type(8))) _Float16 f16x8;
typedef __attribute__((ext_vector_type(4))) float    f32x4;

__device__ __forceinline__ float h2fu(u16 u) { union { u16 s; f16 h; } t; t.s = u; return (float)t.h; }
__device__ __forceinline__ u16   f2h(float f) { union { u16 s; f16 h; } t; t.h = (f16)f; return t.s; }
__device__ __forceinline__ float geluf(float u) { return 0.5f*u*(1.0f + erff(u*0.70710678118654752f)); }
__device__ __forceinline__ float sigmf(float x) { return 1.0f/(1.0f + __expf(-x)); }
__device__ __forceinline__ float tanhfast(float x) { return 1.0f - 2.0f/(__expf(2.0f*x) + 1.0f); }

// ---------------------------------------------------------------------------
// Fused conv1(1->32,k7,p3)+bn+gelu -> conv2(32->64,k5,s2,p2)+bn+gelu.
// (unchanged from round 6 — validated)
// ---------------------------------------------------------------------------
__global__ __launch_bounds__(256) void k_conv(
    const float* __restrict__ x,
    const float* __restrict__ w1, const float* __restrict__ cb1v,
    const float* __restrict__ g1v, const float* __restrict__ be1v,
    const float* __restrict__ w2, const float* __restrict__ cb2v,
    const float* __restrict__ g2v, const float* __restrict__ be2v,
    f16* __restrict__ feat) {
  __shared__ float xs[262];
  __shared__ __align__(16) u16 ylh[32*260];
  __shared__ __align__(16) u16 wth[160*64];
  __shared__ float w1l[224];
  __shared__ float cb1[32], sc1[32], sb1[32];
  __shared__ float cb2[64], sc2[64], sb2[64];
  int r = blockIdx.x, tid = threadIdx.x;
  int bb = r >> 4, n = r & 15;
  for (int i = tid; i < 262; i += 256) {
    int p = i - 3;
    xs[i] = (p >= 0 && p < 256) ? x[(size_t)r*256 + p] : 0.0f;
  }
  if (tid < 224) {
    w1l[tid] = w1[tid];
  } else {
    int oc = tid - 224;
    cb1[oc] = cb1v[oc];
    sc1[oc] = g1v[oc] * rsqrtf(1.0f + 1e-5f);
    sb1[oc] = be1v[oc];
  }
  for (int i = tid; i < 10240; i += 256) {
    int rest = i >> 6, oc = i & 63;
    wth[rest*64 + oc] = f2h(w2[oc*160 + rest]);
  }
  if (tid < 64) {
    cb2[tid] = cb2v[tid];
    sc2[tid] = g2v[tid] * rsqrtf(1.0f + 1e-5f);
    sb2[tid] = be2v[tid];
  }
  for (int i = tid; i < 128; i += 256) {
    int ic = i >> 2, z = i & 3;
    ylh[ic*260 + (z < 2 ? z : 256 + z)] = 0;
  }
  __syncthreads();
  float xv[7];
  #pragma unroll
  for (int k = 0; k < 7; k++) xv[k] = xs[tid + k];
  for (int oc = 0; oc < 32; oc++) {
    float acc = cb1[oc];
    #pragma unroll
    for (int k = 0; k < 7; k++) acc += w1l[oc*7 + k]*xv[k];
    float u = acc*sc1[oc] + sb1[oc];
    ylh[oc*260 + 2 + tid] = f2h(geluf(u));
  }
  __syncthreads();
  int oc = tid & 63, t4 = tid >> 6;
  float acc[32];
  #pragma unroll
  for (int q = 0; q < 32; q++) acc[q] = cb2[oc];
  for (int ic = 0; ic < 32; ic++) {
    const u16* wp = &wth[(ic*5)*64 + oc];
    float w0 = h2fu(wp[0]),  ww1 = h2fu(wp[64]),  ww2 = h2fu(wp[128]),
          ww3 = h2fu(wp[192]), ww4 = h2fu(wp[256]);
    const u16* yy = &ylh[ic*260];
    int base = t4*64;
    u32 p0 = *(const u32*)&yy[base];
    u32 p1 = *(const u32*)&yy[base + 2];
    float y0 = h2fu((u16)p0), y1 = h2fu((u16)(p0 >> 16));
    float y2 = h2fu((u16)p1), y3 = h2fu((u16)(p1 >> 16));
    #pragma unroll
    for (int q = 0; q < 32; q++) {
      u32 p2 = *(const u32*)&yy[base + 2*q + 4];
      float y4 = h2fu((u16)p2), y5 = h2fu((u16)(p2 >> 16));
      acc[q] += w0*y0 + ww1*y1 + ww2*y2 + ww3*y3 + ww4*y4;
      y0 = y2; y1 = y3; y2 = y4; y3 = y5;
    }
  }
  #pragma unroll
  for (int q = 0; q < 32; q++) {
    int t2 = t4*32 + q;
    float u = acc[q]*sc2[oc] + sb2[oc];
    feat[(((size_t)bb*128 + t2)*16 + n)*64 + oc] = (f16)geluf(u);
  }
}

// ---------------------------------------------------------------------------
// GAT layer (+ReLU +LayerNorm) via MFMA.  (unchanged — validated)
// ---------------------------------------------------------------------------
template<int F>
__global__ __launch_bounds__(256) void k_gat_mfma(
    const f16* __restrict__ xin, const float* __restrict__ W,
    const float* __restrict__ asrc, const float* __restrict__ adst,
    const float* __restrict__ gng, const float* __restrict__ gnb,
    f16* __restrict__ gout) {
  constexpr int XP = F + 8;
  __shared__ __align__(16) u16 xa[128*XP];
  __shared__ __align__(16) u16 wt[128*XP];
  __shared__ float hb[128*129];
  __shared__ float esl[512], edl[512];
  __shared__ float wsv[128], wdv[128];
  int tid = threadIdx.x;
  size_t rowbase = (size_t)blockIdx.x*128;
  const u32* xg = (const u32*)(xin + rowbase*F);
  for (int i = tid; i < 128*F/2; i += 256) {
    u32 v = xg[i];
    int r = (2*i)/F, k = (2*i)%F;
    *(u32*)&xa[r*XP + k] = v;
  }
  for (int i = tid; i < F*128; i += 256) {
    int k = i >> 7, c = i & 127;
    wt[c*XP + k] = f2h(W[i]);
  }
  if (tid < 128) { wsv[tid] = asrc[tid]; wdv[tid] = adst[tid]; }
  __syncthreads();
  int wave = tid >> 6, lane = tid & 63;
  int lr = lane & 15, lg = lane >> 4;
  #pragma unroll
  for (int mi = 0; mi < 2; mi++) {
    int mt = wave*2 + mi;
    f16x8 af[F/32];
    #pragma unroll
    for (int kb = 0; kb < F/32; kb++)
      af[kb] = *(const f16x8*)&xa[(mt*16 + lr)*XP + kb*32 + lg*8];
    #pragma unroll
    for (int nt = 0; nt < 8; nt++) {
      f32x4 acc = {0.0f, 0.0f, 0.0f, 0.0f};
      #pragma unroll
      for (int kb = 0; kb < F/32; kb++) {
        f16x8 bf = *(const f16x8*)&wt[(nt*16 + lr)*XP + kb*32 + lg*8];
        acc = __builtin_amdgcn_mfma_f32_16x16x32_f16(af[kb], bf, acc, 0, 0, 0);
      }
      #pragma unroll
      for (int q = 0; q < 4; q++)
        hb[(mt*16 + lg*4 + q)*129 + nt*16 + lr] = acc[q];
    }
  }
  __syncthreads();
  int g = tid >> 5, l32 = tid & 31;
  #pragma unroll
  for (int q = 0; q < 2; q++) {
    int p = l32 + 32*q;
    int n = p >> 2, hh = p & 3;
    const float* hp  = &hb[(g*16 + n)*129 + hh*32];
    const float* wsp = &wsv[hh*32];
    const float* wdp = &wdv[hh*32];
    float es = 0.0f, ed = 0.0f;
    #pragma unroll
    for (int d = 0; d < 32; d++) { float hv = hp[d]; es += hv*wsp[d]; ed += hv*wdp[d]; }
    esl[g*64 + p] = es; edl[g*64 + p] = ed;
  }
  __syncthreads();
  u16* al = xa;
  #pragma unroll
  for (int q = 0; q < 2; q++) {
    int p = l32 + 32*q;
    int i = p >> 2, hh = p & 3;
    float ei = esl[g*64 + p];
    float pv[16]; float mx = -1e30f;
    #pragma unroll
    for (int j = 0; j < 16; j++) {
      float e = ei + edl[g*64 + j*4 + hh];
      e = (e < 0.0f) ? 0.2f*e : e;
      pv[j] = e; mx = fmaxf(mx, e);
    }
    float sum = 0.0f;
    #pragma unroll
    for (int j = 0; j < 16; j++) { float pe = __expf(pv[j] - mx); pv[j] = pe; sum += pe; }
    float inv = 1.0f/sum;
    u16* ap = &al[((g*4 + hh)*16 + i)*16];
    #pragma unroll
    for (int j = 0; j < 16; j++) ap[j] = f2h(pv[j]*inv);
  }
  __syncthreads();
  int rloc = tid >> 1;
  int gg = rloc >> 4, ii = rloc & 15;
  int half = tid & 1;
  float o[64];
  #pragma unroll
  for (int hhh = 0; hhh < 2; hhh++) {
    int hh = half*2 + hhh;
    const u16* ap = &al[((gg*4 + hh)*16 + ii)*16];
    f16x8 a0 = *(const f16x8*)&ap[0];
    f16x8 a1 = *(const f16x8*)&ap[8];
    float aw[16];
    #pragma unroll
    for (int j = 0; j < 8; j++) { aw[j] = (float)a0[j]; aw[8 + j] = (float)a1[j]; }
    #pragma unroll
    for (int dd = 0; dd < 32; dd++) {
      int d = hh*32 + dd;
      float acc = 0.0f;
      #pragma unroll
      for (int j = 0; j < 16; j++) acc += aw[j]*hb[(gg*16 + j)*129 + d];
      o[hhh*32 + dd] = fmaxf(acc, 0.0f);
    }
  }
  float s = 0.0f, sq = 0.0f;
  #pragma unroll
  for (int k = 0; k < 64; k++) { s += o[k]; sq += o[k]*o[k]; }
  s  += __shfl_xor(s, 1);
  sq += __shfl_xor(sq, 1);
  float mean = s*(1.0f/128.0f);
  float var  = sq*(1.0f/128.0f) - mean*mean;
  float rstd = rsqrtf(var + 1e-5f);
  f16* orow = gout + (rowbase + rloc)*128 + half*64;
  #pragma unroll
  for (int k = 0; k < 64; k++) {
    int d = half*64 + k;
    orow[k] = (f16)((o[k] - mean)*rstd*gng[d] + gnb[d]);
  }
}

// ---------------------------------------------------------------------------
// MFMA GEMM (unchanged — validated): C[M,N](f16) = A@W^T + bias1(+bias2).
// ---------------------------------------------------------------------------
__global__ __launch_bounds__(256) void k_gemm_mfma(
    const f16* __restrict__ A, const float* __restrict__ W,
    const float* __restrict__ bias1, const float* __restrict__ bias2,
    f16* __restrict__ C, int M, int N, int K) {
  __shared__ __align__(16) u16 As[128*64];
  __shared__ __align__(16) u16 Bs[128*64];
  int tid = threadIdx.x;
  int wave = tid >> 6, lane = tid & 63;
  int wm = wave >> 1, wn = wave & 1;
  int lr = lane & 15, lg = lane >> 4;
  int m0 = blockIdx.x << 7, n0 = blockIdx.y << 7;
  f32x4 acc[4][4];
  #pragma unroll
  for (int mi = 0; mi < 4; mi++)
    #pragma unroll
    for (int ni = 0; ni < 4; ni++)
      acc[mi][ni] = (f32x4){0.0f, 0.0f, 0.0f, 0.0f};
  for (int k0 = 0; k0 < K; k0 += 64) {
    uint4  a_st[4];
    float4 b_st[4][2];
    #pragma unroll
    for (int it = 0; it < 4; it++) {
      int cc = it*256 + tid;
      int r = cc >> 3, s = cc & 7;
      int kk = k0 + (((s ^ (r & 7))) << 3);
      a_st[it] = *(const uint4*)((const u16*)A + (size_t)(m0 + r)*K + kk);
      const float* wp = W + (size_t)(n0 + r)*K + kk;
      b_st[it][0] = *(const float4*)wp;
      b_st[it][1] = *(const float4*)(wp + 4);
    }
    __syncthreads();
    #pragma unroll
    for (int it = 0; it < 4; it++) {
      int cc = it*256 + tid;
      *(uint4*)&As[cc*8] = a_st[it];
      union { uint4 u; f16 h[8]; } bb;
      float4 x = b_st[it][0], y = b_st[it][1];
      bb.h[0] = (f16)x.x; bb.h[1] = (f16)x.y; bb.h[2] = (f16)x.z; bb.h[3] = (f16)x.w;
      bb.h[4] = (f16)y.x; bb.h[5] = (f16)y.y; bb.h[6] = (f16)y.z; bb.h[7] = (f16)y.w;
      *(uint4*)&Bs[cc*8] = bb.u;
    }
    __syncthreads();
    #pragma unroll
    for (int ks = 0; ks < 2; ks++) {
      f16x8 af[4], bf[4];
      #pragma unroll
      for (int mi = 0; mi < 4; mi++) {
        int row = wm*64 + mi*16 + lr;
        int slot = (ks*4 + lg) ^ (row & 7);
        af[mi] = *(const f16x8*)&As[row*64 + slot*8];
      }
      #pragma unroll
      for (int ni = 0; ni < 4; ni++) {
        int row = wn*64 + ni*16 + lr;
        int slot = (ks*4 + lg) ^ (row & 7);
        bf[ni] = *(const f16x8*)&Bs[row*64 + slot*8];
      }
      #pragma unroll
      for (int mi = 0; mi < 4; mi++)
        #pragma unroll
        for (int ni = 0; ni < 4; ni++)
          acc[mi][ni] = __builtin_amdgcn_mfma_f32_16x16x32_f16(af[mi], bf[ni], acc[mi][ni], 0, 0, 0);
    }
  }
  #pragma unroll
  for (int ni = 0; ni < 4; ni++) {
    int coln = n0 + wn*64 + ni*16 + lr;
    float bv = bias1[coln];
    if (bias2) bv += bias2[coln];
    #pragma unroll
    for (int mi = 0; mi < 4; mi++) {
      int rowm = m0 + wm*64 + mi*16 + lg*4;
      #pragma unroll
      for (int q = 0; q < 4; q++)
        C[(size_t)(rowm + q)*N + coln] = (f16)(acc[mi][ni][q] + bv);
    }
  }
}

// ---------------------------------------------------------------------------
// LSTM recurrence via MFMA.  One block = 16 sequences x 1 dir (grid 32),
// 512 threads = 8 waves.  Per step: gates[16x512] = H[16x128] @ whh^T as
// M=16,N=512,K=128 MFMA GEMM; whh fragments resident in REGISTERS (4nt x 4kb
// f16x8 per wave).  H in f16 LDS (stride 136: 2-way bank alias only).
// Activation: thread owns (seq g_a, units u0..u0+3), c-state in registers,
// next-step pre prefetched into registers (hides HBM latency).
// ---------------------------------------------------------------------------
__global__ __launch_bounds__(512) void k_lstm_mfma(
    const f16* __restrict__ pre_f, const f16* __restrict__ pre_b,
    const float* __restrict__ whh_f, const float* __restrict__ whh_b,
    f16* __restrict__ hout) {
  __shared__ __align__(16) u16 hlh[16*136];     // h (f16), row stride 136
  __shared__ float gl[16*516];                  // gate pre-acts, row stride 516
  int tid = threadIdx.x;
  int dir = blockIdx.x & 1;
  int b0  = (blockIdx.x >> 1) << 4;
  const f16* pre = dir ? pre_b : pre_f;
  const float* whh = dir ? whh_b : whh_f;
  int wave = tid >> 6, lane = tid & 63;
  int lr = lane & 15, lg = lane >> 4;
  // whh B-fragments in registers (validated layout: bf = W^T[col=nt*16+lr][k])
  f16x8 bw[4][4];
  #pragma unroll
  for (int nt = 0; nt < 4; nt++) {
    int j = (wave*4 + nt)*16 + lr;
    #pragma unroll
    for (int kb = 0; kb < 4; kb++) {
      const float* wp = whh + (size_t)j*128 + kb*32 + lg*8;
      f16x8 v;
      #pragma unroll
      for (int e = 0; e < 8; e++) v[e] = (f16)wp[e];
      bw[nt][kb] = v;
    }
  }
  for (int i = tid; i < 16*136; i += 512) hlh[i] = 0;
  int g_a = tid >> 5;                 // sequence 0..15
  int u0  = (tid & 31) << 2;          // unit 0,4,...,124
  size_t prow = (size_t)(b0 + g_a)*128;
  const u16* preu = (const u16*)pre;
  int t0 = dir ? 127 : 0;
  uint2 pi = *(const uint2*)&preu[(prow + t0)*512 + u0];
  uint2 pf = *(const uint2*)&preu[(prow + t0)*512 + 128 + u0];
  uint2 pg = *(const uint2*)&preu[(prow + t0)*512 + 256 + u0];
  uint2 po = *(const uint2*)&preu[(prow + t0)*512 + 384 + u0];
  float c0 = 0.0f, c1 = 0.0f, c2 = 0.0f, c3 = 0.0f;
  u16* houtu = (u16*)hout;
  __syncthreads();
  for (int s = 0; s < 128; s++) {
    int t = dir ? (127 - s) : s;
    // ---- MFMA phase: gates = H @ whh^T ----
    f16x8 af[4];
    #pragma unroll
    for (int kb = 0; kb < 4; kb++)
      af[kb] = *(const f16x8*)&hlh[lr*136 + kb*32 + lg*8];
    #pragma unroll
    for (int nt = 0; nt < 4; nt++) {
      f32x4 acc = {0.0f, 0.0f, 0.0f, 0.0f};
      #pragma unroll
      for (int kb = 0; kb < 4; kb++)
        acc = __builtin_amdgcn_mfma_f32_16x16x32_f16(af[kb], bw[nt][kb], acc, 0, 0, 0);
      int jc = (wave*4 + nt)*16 + lr;
      #pragma unroll
      for (int q = 0; q < 4; q++)
        gl[(lg*4 + q)*516 + jc] = acc[q];
    }
    __syncthreads();
    // ---- activation phase ----
    float4 gi4 = *(const float4*)&gl[g_a*516 + u0];
    float4 gf4 = *(const float4*)&gl[g_a*516 + 128 + u0];
    float4 gg4 = *(const float4*)&gl[g_a*516 + 256 + u0];
    float4 go4 = *(const float4*)&gl[g_a*516 + 384 + u0];
    uint2 ni = pi, nf = pf, ng = pg, no = po;
    if (s < 127) {
      int tn = dir ? (126 - s) : (s + 1);
      pi = *(const uint2*)&preu[(prow + tn)*512 + u0];
      pf = *(const uint2*)&preu[(prow + tn)*512 + 128 + u0];
      pg = *(const uint2*)&preu[(prow + tn)*512 + 256 + u0];
      po = *(const uint2*)&preu[(prow + tn)*512 + 384 + u0];
    }
    float iv0 = gi4.x + h2fu((u16)ni.x), iv1 = gi4.y + h2fu((u16)(ni.x >> 16)),
          iv2 = gi4.z + h2fu((u16)ni.y), iv3 = gi4.w + h2fu((u16)(ni.y >> 16));
    float fv0 = gf4.x + h2fu((u16)nf.x), fv1 = gf4.y + h2fu((u16)(nf.x >> 16)),
          fv2 = gf4.z + h2fu((u16)nf.y), fv3 = gf4.w + h2fu((u16)(nf.y >> 16));
    float gv0 = gg4.x + h2fu((u16)ng.x), gv1 = gg4.y + h2fu((u16)(ng.x >> 16)),
          gv2 = gg4.z + h2fu((u16)ng.y), gv3 = gg4.w + h2fu((u16)(ng.y >> 16));
    float ov0 = go4.x + h2fu((u16)no.x), ov1 = go4.y + h2fu((u16)(no.x >> 16)),
          ov2 = go4.z + h2fu((u16)no.y), ov3 = go4.w + h2fu((u16)(no.y >> 16));
    c0 = sigmf(fv0)*c0 + sigmf(iv0)*tanhfast(gv0);
    c1 = sigmf(fv1)*c1 + sigmf(iv1)*tanhfast(gv1);
    c2 = sigmf(fv2)*c2 + sigmf(iv2)*tanhfast(gv2);
    c3 = sigmf(fv3)*c3 + sigmf(iv3)*tanhfast(gv3);
    float h0 = sigmf(ov0)*tanhfast(c0);
    float h1 = sigmf(ov1)*tanhfast(c1);
    float h2 = sigmf(ov2)*tanhfast(c2);
    float h3 = sigmf(ov3)*tanhfast(c3);
    ushort4 hw;
    hw.x = f2h(h0); hw.y = f2h(h1); hw.z = f2h(h2); hw.w = f2h(h3);
    *(ushort4*)&hlh[g_a*136 + u0] = hw;
    *(ushort4*)&houtu[(prow + t)*256 + (dir << 7) + u0] = hw;
    __syncthreads();
  }
}

// ---------------------------------------------------------------------------
// MHA core: one block per (batch, head).  (unchanged)
// ---------------------------------------------------------------------------
__global__ __launch_bounds__(256) void k_mha(const f16* __restrict__ qkv, f16* __restrict__ o) {
  __shared__ float ql[128*66];
  __shared__ float kl[128*66];
  __shared__ u16   sl[128*132];
  __shared__ float invl[128];
  int b = blockIdx.x, h = blockIdx.y, tid = threadIdx.x;
  const f16* base = qkv + (size_t)b*98304 + h*64;
  for (int i = tid; i < 8192; i += 256) {
    int t = i >> 6, d = i & 63;
    ql[t*66 + d] = (float)base[t*768 + d];
    kl[t*66 + d] = (float)base[t*768 + 256 + d];
  }
  __syncthreads();
  int i = tid >> 1, jh = (tid & 1) << 6;
  const float* qp = &ql[i*66];
  float mx = -1e30f;
  for (int j = 0; j < 64; j++) {
    const float* kp = &kl[(jh + j)*66];
    float acc = 0.0f;
    #pragma unroll 8
    for (int d = 0; d < 64; d += 2) {
      float2 qv = *(const float2*)&qp[d];
      float2 kv = *(const float2*)&kp[d];
      acc += qv.x*kv.x + qv.y*kv.y;
    }
    acc *= 0.125f;
    sl[i*132 + jh + j] = f2h(acc);
    mx = fmaxf(mx, acc);
  }
  mx = fmaxf(mx, __shfl_xor(mx, 1));
  float sum = 0.0f;
  u16* sp = &sl[i*132 + jh];
  for (int j = 0; j < 64; j++) {
    float e = __expf(h2fu(sp[j]) - mx);
    sp[j] = f2h(e);
    sum += e;
  }
  sum += __shfl_xor(sum, 1);
  if ((tid & 1) == 0) invl[i] = 1.0f/sum;
  __syncthreads();
  for (int i2 = tid; i2 < 8192; i2 += 256) {
    int t = i2 >> 6, d = i2 & 63;
    ql[t*66 + d] = (float)base[t*768 + 512 + d];
  }
  __syncthreads();
  for (int it = 0; it < 32; it++) {
    int idx = it*256 + tid;
    int oi = idx >> 6, d = idx & 63;
    const u16* pp = &sl[oi*132];
    float acc = 0.0f;
    #pragma unroll 16
    for (int j = 0; j < 128; j++) acc += h2fu(pp[j])*ql[j*66 + d];
    o[((size_t)b*128 + oi)*256 + h*64 + d] = (f16)(acc*invl[oi]);
  }
}

// ---------------------------------------------------------------------------
// att = LayerNorm(mha_out + lstm_out), width 256.  (unchanged)
// ---------------------------------------------------------------------------
__global__ __launch_bounds__(256) void k_lnres(
    const f16* __restrict__ a, const f16* __restrict__ r,
    const float* __restrict__ g, const float* __restrict__ bb, f16* __restrict__ out) {
  int row = blockIdx.x*4 + (threadIdx.x >> 6);
  int lane = threadIdx.x & 63;
  const f16* ar = a + (size_t)row*256 + lane*4;
  const f16* rr = r + (size_t)row*256 + lane*4;
  float v0 = (float)ar[0] + (float)rr[0];
  float v1 = (float)ar[1] + (float)rr[1];
  float v2 = (float)ar[2] + (float)rr[2];
  float v3 = (float)ar[3] + (float)rr[3];
  float s = v0 + v1 + v2 + v3;
  float q = v0*v0 + v1*v1 + v2*v2 + v3*v3;
  #pragma unroll
  for (int off = 32; off; off >>= 1) { s += __shfl_xor(s, off); q += __shfl_xor(q, off); }
  float mean = s*(1.0f/256.0f);
  float var  = q*(1.0f/256.0f) - mean*mean;
  float rstd = rsqrtf(var + 1e-5f);
  int d0 = lane*4;
  f16* op = out + (size_t)row*256 + d0;
  op[0] = (f16)((v0 - mean)*rstd*g[d0+0] + bb[d0+0]);
  op[1] = (f16)((v1 - mean)*rstd*g[d0+1] + bb[d0+1]);
  op[2] = (f16)((v2 - mean)*rstd*g[d0+2] + bb[d0+2]);
  op[3] = (f16)((v3 - mean)*rstd*g[d0+3] + bb[d0+3]);
}

// ---------------------------------------------------------------------------
// mean/max pool over T, LayerNorm(512), cls1+ReLU, cls2.  (unchanged)
// ---------------------------------------------------------------------------
__global__ __launch_bounds__(512) void k_pool_cls(
    const f16* __restrict__ att, const float* __restrict__ png, const float* __restrict__ pnb,
    const float* __restrict__ w1, const float* __restrict__ b1,
    const float* __restrict__ w2, const float* __restrict__ b2, float* __restrict__ out) {
  __shared__ float pl[512];
  __shared__ float redS[8], redQ[8];
  __shared__ float mrv[2];
  __shared__ float hl[128];
  int b = blockIdx.x, tid = threadIdx.x;
  if (tid < 256) {
    const f16* ar = att + (size_t)b*32768 + tid;
    float s = 0.0f, mx = -1e30f;
    for (int t = 0; t < 128; t++) { float v = (float)ar[t*256]; s += v; mx = fmaxf(mx, v); }
    pl[tid] = s*(1.0f/128.0f);
    pl[256 + tid] = mx;
  }
  __syncthreads();
  float v = pl[tid];
  float s = v, q = v*v;
  #pragma unroll
  for (int off = 32; off; off >>= 1) { s += __shfl_xor(s, off); q += __shfl_xor(q, off); }
  if ((tid & 63) == 0) { redS[tid >> 6] = s; redQ[tid >> 6] = q; }
  __syncthreads();
  if (tid == 0) {
    float S = 0.0f, Q = 0.0f;
    #pragma unroll
    for (int w = 0; w < 8; w++) { S += redS[w]; Q += redQ[w]; }
    float mean = S*(1.0f/512.0f);
    float var  = Q*(1.0f/512.0f) - mean*mean;
    mrv[0] = mean; mrv[1] = rsqrtf(var + 1e-5f);
  }
  __syncthreads();
  pl[tid] = (v - mrv[0])*mrv[1]*png[tid] + pnb[tid];
  __syncthreads();
  if (tid < 128) {
    float acc = b1[tid];
    const float* wrp = w1 + (size_t)tid*512;
    for (int d = 0; d < 512; d++) acc += pl[d]*wrp[d];
    hl[tid] = fmaxf(acc, 0.0f)*w2[tid];
  }
  __syncthreads();
  if (tid < 64) {
    float rsum = hl[tid] + hl[tid + 64];
    #pragma unroll
    for (int off = 32; off; off >>= 1) rsum += __shfl_xor(rsum, off);
    if (tid == 0) out[b] = rsum + b2[0];
  }
}

// ---------------------------------------------------------------------------
extern "C" void kernel_launch(void* const* d_in, const int* in_sizes, int n_in,
                              void* d_out, int out_size, void* d_ws, size_t ws_size,
                              hipStream_t stream) {
  (void)in_sizes; (void)n_in; (void)out_size;
  if (ws_size < (size_t)192*1024*1024) return;
  const float* IN[47];
  for (int i = 0; i < 47; i++) IN[i] = (const float*)d_in[i];
  char* W8 = (char*)d_ws;
  f16* feat     = (f16*)(W8 + ((size_t)0  << 20));  // [0,64)   dead after GAT1
  f16* g        = (f16*)(W8 + ((size_t)64 << 20));  // [64,192) dead after pre GEMMs
  f16* pre_f    = (f16*)(W8 + ((size_t)0  << 20));  // [0,32)
  f16* pre_b    = (f16*)(W8 + ((size_t)32 << 20));  // [32,64)
  f16* h1       = (f16*)(W8 + ((size_t)64 << 20));  // [64,80)
  f16* lstm_out = (f16*)(W8 + ((size_t)80 << 20));  // [80,96)  live till lnres
  f16* qkv      = (f16*)(W8 + ((size_t)96 << 20));  // [96,144)
  f16* o_flat   = (f16*)(W8 + ((size_t)0  << 20));  // [0,16)
  f16* mo       = (f16*)(W8 + ((size_t)16 << 20));  // [16,32)
  f16* att      = (f16*)(W8 + ((size_t)32 << 20));  // [32,48)

  k_conv<<<4096, 256, 0, stream>>>(IN[0], IN[1], IN[2], IN[3], IN[4],
                                   IN[5], IN[6], IN[7], IN[8], feat);
  k_gat_mfma<64><<<4096, 256, 0, stream>>>(feat, IN[9], IN[10], IN[11], IN[12], IN[13], g);
  k_gat_mfma<128><<<4096, 256, 0, stream>>>(g, IN[14], IN[15], IN[16], IN[17], IN[18], g);
  k_gemm_mfma<<<dim3(256, 4), 256, 0, stream>>>(g, IN[19], IN[21], IN[22], pre_f, 32768, 512, 2048);
  k_gemm_mfma<<<dim3(256, 4), 256, 0, stream>>>(g, IN[23], IN[25], IN[26], pre_b, 32768, 512, 2048);
  k_lstm_mfma<<<32, 512, 0, stream>>>(pre_f, pre_b, IN[20], IN[24], h1);
  k_gemm_mfma<<<dim3(256, 4), 256, 0, stream>>>(h1, IN[27], IN[29], IN[30], pre_f, 32768, 512, 256);
  k_gemm_mfma<<<dim3(256, 4), 256, 0, stream>>>(h1, IN[31], IN[33], IN[34], pre_b, 32768, 512, 256);
  k_lstm_mfma<<<32, 512, 0, stream>>>(pre_f, pre_b, IN[28], IN[32], lstm_out);
  k_gemm_mfma<<<dim3(256, 6), 256, 0, stream>>>(lstm_out, IN[35], IN[36], nullptr, qkv, 32768, 768, 256);
  k_mha<<<dim3(256, 4), 256, 0, stream>>>(qkv, o_flat);
  k_gemm_mfma<<<dim3(256, 2), 256, 0, stream>>>(o_flat, IN[37], IN[38], nullptr, mo, 32768, 256, 256);
  k_lnres<<<8192, 256, 0, stream>>>(mo, lstm_out, IN[39], IN[40], att);
  k_pool_cls<<<256, 512, 0, stream>>>(att, IN[41], IN[42], IN[43], IN[44], IN[45], IN[46],
                                      (float*)d_out);
}